// Round 1
// baseline (1137.758 us; speedup 1.0000x reference)
//
#include <hip/hip_runtime.h>
#include <type_traits>

// ---------------------------------------------------------------------------
// GPT block forward: B=2, S=2048, D=1024, H=16, DH=64
//  qkv = x@Wattn+b ; attn(causal) ; a@Waproj+b ; n=LN(x+a)
//  h = gelu(n@Wfc+b) ; m = h@Wmproj+b ; out = LN(n+m)
// bf16 MFMA compute (fp32 accumulate); threshold is 8*bf16eps*max|ref|.
// ---------------------------------------------------------------------------

typedef unsigned short u16;
typedef short s16x8 __attribute__((ext_vector_type(8)));
typedef unsigned short u16x4 __attribute__((ext_vector_type(4)));
typedef float f32x4 __attribute__((ext_vector_type(4)));

__device__ __forceinline__ u16 f2b(float f) {
    union { float f; unsigned u; } x{f};
    unsigned r = x.u + 0x7FFFu + ((x.u >> 16) & 1u);  // RNE
    return (u16)(r >> 16);
}

__device__ __forceinline__ f32x4 mfma16(s16x8 a, s16x8 b, f32x4 c) {
    return __builtin_amdgcn_mfma_f32_16x16x32_bf16(a, b, c, 0, 0, 0);
}

// --------------------------- fp32 -> bf16 convert ---------------------------
__global__ __launch_bounds__(256) void cvt_bf16(const float* __restrict__ in,
                                                u16* __restrict__ out, int n4) {
    int i = blockIdx.x * 256 + threadIdx.x;
    if (i < n4) {
        float4 v = ((const float4*)in)[i];
        u16x4 o = {f2b(v.x), f2b(v.y), f2b(v.z), f2b(v.w)};
        ((u16x4*)out)[i] = o;
    }
}

// ------------------- transpose fp32 [K,N] -> bf16 [N,K] ---------------------
__global__ __launch_bounds__(256) void transpose_bf16(const float* __restrict__ W,
                                                      u16* __restrict__ WT,
                                                      int K, int N) {
    __shared__ float t[32][33];
    int tx = threadIdx.x & 31, ty = threadIdx.x >> 5;
    int n0 = blockIdx.x * 32, k0 = blockIdx.y * 32;
    #pragma unroll
    for (int r = ty; r < 32; r += 8)
        t[r][tx] = W[(size_t)(k0 + r) * N + n0 + tx];
    __syncthreads();
    #pragma unroll
    for (int r = ty; r < 32; r += 8)
        WT[(size_t)(n0 + r) * K + k0 + tx] = f2b(t[tx][r]);
}

// ----------------------------- MFMA GEMM ------------------------------------
// C[M,ldc] = A[M,K](bf16) @ BT[N,K]^T (bf16) + bias ; optional GELU; OT out.
// block: 256 thr = 4 waves; block tile 32(M) x 128(N); wave tile 16 x 64.
template<bool GELU, typename OT>
__global__ __launch_bounds__(256) void gemm_bt(const u16* __restrict__ A,
                                               const u16* __restrict__ BT,
                                               const float* __restrict__ bias,
                                               OT* __restrict__ C,
                                               int M, int N, int K, int ldc) {
    int t = threadIdx.x;
    int w = t >> 6, l = t & 63, l16 = l & 15, lh = l >> 4;
    size_t m0 = (size_t)blockIdx.x * 32 + (size_t)(w & 1) * 16;
    size_t n0 = (size_t)blockIdx.y * 128 + (size_t)(w >> 1) * 64;
    const u16* Ap = A + (m0 + l16) * (size_t)K + lh * 8;
    const u16* Bp = BT + (n0 + l16) * (size_t)K + lh * 8;
    f32x4 acc[4] = {};
    #pragma unroll 2
    for (int k0 = 0; k0 < K; k0 += 32) {
        s16x8 a = *(const s16x8*)(Ap + k0);
        #pragma unroll
        for (int f = 0; f < 4; ++f) {
            s16x8 b = *(const s16x8*)(Bp + (size_t)f * 16 * K + k0);
            acc[f] = mfma16(a, b, acc[f]);
        }
    }
    #pragma unroll
    for (int f = 0; f < 4; ++f) {
        size_t col = n0 + f * 16 + l16;
        float bs = bias[col];
        #pragma unroll
        for (int i = 0; i < 4; ++i) {
            size_t r = m0 + lh * 4 + i;
            float v = acc[f][i] + bs;
            if constexpr (GELU) {
                float x3 = v * v * v;
                v = 0.5f * v * (1.f + tanhf(0.7978845608f * (v + 0.044715f * x3)));
            }
            if constexpr (std::is_same<OT, u16>::value)
                C[r * ldc + col] = f2b(v);
            else
                C[r * ldc + col] = v;
        }
    }
}

// --------------------------- causal attention -------------------------------
// qkv bf16 [B*S, 3072]; out abuf bf16 [B*S, 1024] (already [B,S,H*DH] order).
// block = (b,h,qtile of 64 rows); 4 waves x 16 q-rows; kv chunks of 32.
__global__ __launch_bounds__(256) void attn_kernel(const u16* __restrict__ qkv,
                                                   u16* __restrict__ abuf) {
    constexpr int S = 2048, D3 = 3072, Dm = 1024, DH = 64;
    __shared__ u16 Kl[32][72];      // kv row, d (pad: 2-way conflicts only)
    __shared__ u16 Vl[64][40];      // d, kv row (transposed)
    __shared__ u16 Pl[4][16][40];   // per-wave P tile

    int t = threadIdx.x;
    int w = t >> 6, l = t & 63, l16 = l & 15, lh = l >> 4;
    int qt = blockIdx.x & 31;
    int bh = blockIdx.x >> 5;
    int b = bh >> 4, h = bh & 15;
    int q0 = qt * 64;
    size_t rowbase = (size_t)b * S * D3;

    int qr = q0 + w * 16 + l16;
    s16x8 qf[2];
    qf[0] = *(const s16x8*)(qkv + rowbase + (size_t)qr * D3 + h * DH + lh * 8);
    qf[1] = *(const s16x8*)(qkv + rowbase + (size_t)qr * D3 + h * DH + 32 + lh * 8);

    f32x4 O[4] = {};
    float mrow[4] = {-1e30f, -1e30f, -1e30f, -1e30f};
    float lrow[4] = {0.f, 0.f, 0.f, 0.f};

    int nch = (q0 + 64) >> 5;
    int qmax = q0 + w * 16 + 15;
    int r32 = t >> 3, c8 = (t & 7) * 8;

    for (int c = 0; c < nch; ++c) {
        // stage K chunk [32][64] and V chunk transposed [64][32]
        int s = c * 32 + r32;
        s16x8 kk = *(const s16x8*)(qkv + rowbase + (size_t)s * D3 + Dm + h * DH + c8);
        *(s16x8*)&Kl[r32][c8] = kk;
        s16x8 vv = *(const s16x8*)(qkv + rowbase + (size_t)s * D3 + 2 * Dm + h * DH + c8);
        #pragma unroll
        for (int j = 0; j < 8; ++j) Vl[c8 + j][r32] = (u16)vv[j];
        __syncthreads();

        if (c * 32 <= qmax) {
            f32x4 s0 = {}, s1 = {};
            s16x8 kf;
            kf = *(const s16x8*)&Kl[l16][lh * 8];           s0 = mfma16(qf[0], kf, s0);
            kf = *(const s16x8*)&Kl[l16][32 + lh * 8];      s0 = mfma16(qf[1], kf, s0);
            kf = *(const s16x8*)&Kl[16 + l16][lh * 8];      s1 = mfma16(qf[0], kf, s1);
            kf = *(const s16x8*)&Kl[16 + l16][32 + lh * 8]; s1 = mfma16(qf[1], kf, s1);

            float al[4];
            #pragma unroll
            for (int i = 0; i < 4; ++i) {
                int qg = q0 + w * 16 + lh * 4 + i;
                int kg0 = c * 32 + l16;
                float v0 = s0[i] * 0.125f; if (kg0 > qg) v0 = -1e30f;
                float v1 = s1[i] * 0.125f; if (kg0 + 16 > qg) v1 = -1e30f;
                float cm = fmaxf(v0, v1);
                cm = fmaxf(cm, __shfl_xor(cm, 1));
                cm = fmaxf(cm, __shfl_xor(cm, 2));
                cm = fmaxf(cm, __shfl_xor(cm, 4));
                cm = fmaxf(cm, __shfl_xor(cm, 8));
                float mn = fmaxf(mrow[i], cm);
                float a_ = __expf(mrow[i] - mn);
                float p0 = __expf(v0 - mn);
                float p1 = __expf(v1 - mn);
                float rs = p0 + p1;
                rs += __shfl_xor(rs, 1);
                rs += __shfl_xor(rs, 2);
                rs += __shfl_xor(rs, 4);
                rs += __shfl_xor(rs, 8);
                lrow[i] = lrow[i] * a_ + rs;
                mrow[i] = mn;
                al[i] = a_;
                Pl[w][lh * 4 + i][l16] = f2b(p0);
                Pl[w][lh * 4 + i][16 + l16] = f2b(p1);
            }
            #pragma unroll
            for (int f = 0; f < 4; ++f) {
                O[f][0] *= al[0]; O[f][1] *= al[1];
                O[f][2] *= al[2]; O[f][3] *= al[3];
            }
            s16x8 pf = *(const s16x8*)&Pl[w][l16][lh * 8];
            #pragma unroll
            for (int f = 0; f < 4; ++f) {
                s16x8 vf = *(const s16x8*)&Vl[f * 16 + l16][lh * 8];
                O[f] = mfma16(pf, vf, O[f]);
            }
        }
        __syncthreads();
    }

    size_t obase = (size_t)b * S * 1024;
    #pragma unroll
    for (int i = 0; i < 4; ++i) {
        float inv = 1.f / lrow[i];
        int qg = q0 + w * 16 + lh * 4 + i;
        #pragma unroll
        for (int f = 0; f < 4; ++f)
            abuf[obase + (size_t)qg * 1024 + h * DH + f * 16 + l16] = f2b(O[f][i] * inv);
    }
}

// --------------------- residual + LayerNorm (row = 1024) --------------------
// out = g * (x1+x2 - mean)/(std+eps) + b   (std = sqrt(sum(d^2)/(N-1)), eps on std)
template<bool WB>
__global__ __launch_bounds__(256) void resln(const float* __restrict__ xa,
                                             const float* __restrict__ xb2,
                                             const float* __restrict__ g,
                                             const float* __restrict__ be,
                                             float* __restrict__ outf,
                                             u16* __restrict__ outb) {
    int row = blockIdx.x;
    int t = threadIdx.x;
    size_t base = (size_t)row * 1024 + t * 4;
    float4 va = *(const float4*)(xa + base);
    float4 vb = *(const float4*)(xb2 + base);
    float v0 = va.x + vb.x, v1 = va.y + vb.y, v2 = va.z + vb.z, v3 = va.w + vb.w;
    float s1 = v0 + v1 + v2 + v3;
    float s2 = v0 * v0 + v1 * v1 + v2 * v2 + v3 * v3;
    #pragma unroll
    for (int off = 32; off >= 1; off >>= 1) {
        s1 += __shfl_down(s1, off);
        s2 += __shfl_down(s2, off);
    }
    __shared__ float r1[4], r2[4];
    if ((t & 63) == 0) { r1[t >> 6] = s1; r2[t >> 6] = s2; }
    __syncthreads();
    s1 = r1[0] + r1[1] + r1[2] + r1[3];
    s2 = r2[0] + r2[1] + r2[2] + r2[3];
    float mean = s1 * (1.f / 1024.f);
    float var = fmaxf((s2 - 1024.f * mean * mean) * (1.f / 1023.f), 0.f);
    float inv = 1.f / (sqrtf(var) + 1e-6f);
    int col = t * 4;
    float y0 = g[col + 0] * ((v0 - mean) * inv) + be[col + 0];
    float y1 = g[col + 1] * ((v1 - mean) * inv) + be[col + 1];
    float y2 = g[col + 2] * ((v2 - mean) * inv) + be[col + 2];
    float y3 = g[col + 3] * ((v3 - mean) * inv) + be[col + 3];
    float4 o = {y0, y1, y2, y3};
    *(float4*)(outf + base) = o;
    if constexpr (WB) {
        u16x4 ob = {f2b(y0), f2b(y1), f2b(y2), f2b(y3)};
        *(u16x4*)(outb + base) = ob;
    }
}

// ---------------------------------------------------------------------------
extern "C" void kernel_launch(void* const* d_in, const int* in_sizes, int n_in,
                              void* d_out, int out_size, void* d_ws, size_t ws_size,
                              hipStream_t stream) {
    (void)in_sizes; (void)n_in; (void)out_size; (void)ws_size;
    const float* x       = (const float*)d_in[0];
    const float* w_attn  = (const float*)d_in[1];
    const float* b_attn  = (const float*)d_in[2];
    const float* w_aproj = (const float*)d_in[3];
    const float* b_aproj = (const float*)d_in[4];
    const float* g1      = (const float*)d_in[5];
    const float* b1      = (const float*)d_in[6];
    const float* w_fc    = (const float*)d_in[7];
    const float* b_fc    = (const float*)d_in[8];
    const float* w_mproj = (const float*)d_in[9];
    const float* b_mproj = (const float*)d_in[10];
    const float* g2      = (const float*)d_in[11];
    const float* b2      = (const float*)d_in[12];
    float* out = (float*)d_out;

    constexpr int M = 4096;           // B*S
    constexpr int D = 1024;

    // workspace arena (80 MiB), lifetimes reused
    char* ws = (char*)d_ws;
    u16*   slotA = (u16*)ws;                         // 32 MiB: qkv -> h
    char*  pB    = ws + (32u << 20);                 //  8 MiB: xb -> abuf -> nb
    char*  pC    = ws + (40u << 20);                 //  8 MiB: weight transpose
    char*  pD    = ws + (48u << 20);                 // 16 MiB: aout -> mout
    char*  pE    = ws + (64u << 20);                 // 16 MiB: n (fp32)

    u16*   xb   = (u16*)pB;
    u16*   wT   = (u16*)pC;
    u16*   qkv  = slotA;
    u16*   abuf = (u16*)pB;
    float* aout = (float*)pD;
    float* nbuf = (float*)pE;
    u16*   nb   = (u16*)pB;
    u16*   h    = slotA;
    float* mout = (float*)pD;

    dim3 blk(256);

    // 1) x -> bf16
    cvt_bf16<<<dim3(4096), blk, 0, stream>>>(x, xb, M * D / 4);

    // 2) Wattn^T ; qkv = xb @ Wattn + b_attn (bf16 out, ldc=3072)
    transpose_bf16<<<dim3(3072 / 32, 1024 / 32), blk, 0, stream>>>(w_attn, wT, 1024, 3072);
    gemm_bt<false, u16><<<dim3(M / 32, 3072 / 128), blk, 0, stream>>>(
        xb, wT, b_attn, qkv, M, 3072, 1024, 3072);

    // 3) causal attention -> abuf (bf16 [B,S,D])
    attn_kernel<<<dim3(1024), blk, 0, stream>>>(qkv, abuf);

    // 4) Waproj^T ; aout = abuf @ Waproj + b_aproj (fp32)
    transpose_bf16<<<dim3(1024 / 32, 1024 / 32), blk, 0, stream>>>(w_aproj, wT, 1024, 1024);
    gemm_bt<false, float><<<dim3(M / 32, 1024 / 128), blk, 0, stream>>>(
        abuf, wT, b_aproj, aout, M, 1024, 1024, 1024);

    // 5) n = LN(x + aout) -> nbuf fp32 + nb bf16
    resln<true><<<dim3(M), blk, 0, stream>>>(x, aout, g1, b1, nbuf, nb);

    // 6) Wfc^T ; h = gelu(nb @ Wfc + b_fc) (bf16, ldc=4096)
    transpose_bf16<<<dim3(4096 / 32, 1024 / 32), blk, 0, stream>>>(w_fc, wT, 1024, 4096);
    gemm_bt<true, u16><<<dim3(M / 32, 4096 / 128), blk, 0, stream>>>(
        nb, wT, b_fc, h, M, 4096, 1024, 4096);

    // 7) Wmproj^T ; mout = h @ Wmproj + b_mproj (fp32)
    transpose_bf16<<<dim3(1024 / 32, 4096 / 32), blk, 0, stream>>>(w_mproj, wT, 4096, 1024);
    gemm_bt<false, float><<<dim3(M / 32, 1024 / 128), blk, 0, stream>>>(
        h, wT, b_mproj, mout, M, 1024, 4096, 1024);

    // 8) out = LN(nbuf + mout) fp32
    resln<false><<<dim3(M), blk, 0, stream>>>(nbuf, mout, g2, b2, out, nullptr);
}

// Round 3
// 498.520 us; speedup vs baseline: 2.2823x; 2.2823x over previous
//
#include <hip/hip_runtime.h>
#include <type_traits>

// ---------------------------------------------------------------------------
// GPT block forward: B=2, S=2048, D=1024, H=16, DH=64
// Round 3 (= round 2 resubmit after container death): m97-structure LDS-staged
// MFMA GEMM (128x128 tile, BK=32, global_load_lds width-16, 4 waves,
// 2-barrier K-loop) + bijective XCD swizzle.
// ---------------------------------------------------------------------------

typedef unsigned short u16;
typedef short s16x8 __attribute__((ext_vector_type(8)));
typedef unsigned short u16x4 __attribute__((ext_vector_type(4)));
typedef float f32x4 __attribute__((ext_vector_type(4)));

__device__ __forceinline__ u16 f2b(float f) {
    union { float f; unsigned u; } x{f};
    unsigned r = x.u + 0x7FFFu + ((x.u >> 16) & 1u);  // RNE
    return (u16)(r >> 16);
}

__device__ __forceinline__ f32x4 mfma16(s16x8 a, s16x8 b, f32x4 c) {
    return __builtin_amdgcn_mfma_f32_16x16x32_bf16(a, b, c, 0, 0, 0);
}

__device__ __forceinline__ void gld_lds16(const u16* g, u16* l) {
    __builtin_amdgcn_global_load_lds(
        (const __attribute__((address_space(1))) void*)g,
        (__attribute__((address_space(3))) void*)l, 16, 0, 0);
}

// --------------------------- fp32 -> bf16 convert ---------------------------
__global__ __launch_bounds__(256) void cvt_bf16(const float* __restrict__ in,
                                                u16* __restrict__ out, int n4) {
    int i = blockIdx.x * 256 + threadIdx.x;
    if (i < n4) {
        float4 v = ((const float4*)in)[i];
        u16x4 o = {f2b(v.x), f2b(v.y), f2b(v.z), f2b(v.w)};
        ((u16x4*)out)[i] = o;
    }
}

// ------------------- transpose fp32 [K,N] -> bf16 [N,K] ---------------------
__global__ __launch_bounds__(256) void transpose_bf16(const float* __restrict__ W,
                                                      u16* __restrict__ WT,
                                                      int K, int N) {
    __shared__ float t[32][33];
    int tx = threadIdx.x & 31, ty = threadIdx.x >> 5;
    int n0 = blockIdx.x * 32, k0 = blockIdx.y * 32;
    #pragma unroll
    for (int r = ty; r < 32; r += 8)
        t[r][tx] = W[(size_t)(k0 + r) * N + n0 + tx];
    __syncthreads();
    #pragma unroll
    for (int r = ty; r < 32; r += 8)
        WT[(size_t)(n0 + r) * K + k0 + tx] = f2b(t[tx][r]);
}

// ----------------------- MFMA GEMM (m97 structure) --------------------------
// C[M,ldc] = A[M,K](bf16) @ BT[N,K]^T(bf16) + bias; optional GELU; OT out.
// 256 thr = 4 waves (2x2); block tile 128x128, BK=32; wave tile 64x64.
// Per K-step: 4x global_load_lds_dwordx4, barrier, 8x ds_read_b128,
// 16 MFMA/wave, barrier.  (learn_hip m97: 874-912 TF @4096^3)
template<bool GELU, typename OT>
__global__ __launch_bounds__(256) void gemm_lds(const u16* __restrict__ A,
                                                const u16* __restrict__ BT,
                                                const float* __restrict__ bias,
                                                OT* __restrict__ C,
                                                int M, int N, int K, int ldc) {
    __shared__ u16 As[128 * 32];
    __shared__ u16 Bs[128 * 32];

    int t = threadIdx.x;
    int w = t >> 6, l = t & 63, l16 = l & 15, lh = l >> 4;
    int wr = w >> 1, wc = w & 1;

    // bijective XCD swizzle (all grids here are % 8 == 0); M-major so each
    // XCD chunk shares one B-panel in its private L2.
    int nbm = M >> 7;
    int nwg = gridDim.x;
    int cpx = nwg >> 3;
    int id = blockIdx.x;
    int id2 = (id & 7) * cpx + (id >> 3);
    size_t m0 = (size_t)(id2 % nbm) * 128;
    size_t n0 = (size_t)(id2 / nbm) * 128;

    // staging: granule g = row*4 + kg (16B each); instr j covers g in
    // [j*256, j*256+256); thread t -> g = j*256 + t; LDS linear dest.
    int rowg = t >> 2, kg = t & 3;
    const u16* Ag0 = A + (m0 + rowg) * (size_t)K + kg * 8;
    const u16* Ag1 = A + (m0 + 64 + rowg) * (size_t)K + kg * 8;
    const u16* Bg0 = BT + (n0 + rowg) * (size_t)K + kg * 8;
    const u16* Bg1 = BT + (n0 + 64 + rowg) * (size_t)K + kg * 8;
    u16* As0 = &As[w * 512];
    u16* As1 = &As[2048 + w * 512];
    u16* Bs0 = &Bs[w * 512];
    u16* Bs1 = &Bs[2048 + w * 512];

    f32x4 acc[4][4] = {};

    for (int k0 = 0; k0 < K; k0 += 32) {
        gld_lds16(Ag0 + k0, As0);
        gld_lds16(Ag1 + k0, As1);
        gld_lds16(Bg0 + k0, Bs0);
        gld_lds16(Bg1 + k0, Bs1);
        __syncthreads();   // compiler emits s_waitcnt vmcnt(0) before barrier

        s16x8 af[4], bf[4];
        #pragma unroll
        for (int fm = 0; fm < 4; ++fm)
            af[fm] = *(const s16x8*)&As[(wr * 64 + fm * 16 + l16) * 32 + lh * 8];
        #pragma unroll
        for (int fn = 0; fn < 4; ++fn)
            bf[fn] = *(const s16x8*)&Bs[(wc * 64 + fn * 16 + l16) * 32 + lh * 8];
        #pragma unroll
        for (int fm = 0; fm < 4; ++fm)
            #pragma unroll
            for (int fn = 0; fn < 4; ++fn)
                acc[fm][fn] = mfma16(af[fm], bf[fn], acc[fm][fn]);
        __syncthreads();
    }

    #pragma unroll
    for (int fn = 0; fn < 4; ++fn) {
        size_t col = n0 + wc * 64 + fn * 16 + l16;
        float bs = bias[col];
        #pragma unroll
        for (int fm = 0; fm < 4; ++fm) {
            size_t row0 = m0 + wr * 64 + fm * 16 + lh * 4;
            #pragma unroll
            for (int i = 0; i < 4; ++i) {
                float v = acc[fm][fn][i] + bs;
                if constexpr (GELU) {
                    float x3 = v * v * v;
                    v = 0.5f * v * (1.f + tanhf(0.7978845608f * (v + 0.044715f * x3)));
                }
                if constexpr (std::is_same<OT, u16>::value)
                    C[(row0 + i) * ldc + col] = f2b(v);
                else
                    C[(row0 + i) * ldc + col] = v;
            }
        }
    }
}

// --------------------------- causal attention -------------------------------
__global__ __launch_bounds__(256) void attn_kernel(const u16* __restrict__ qkv,
                                                   u16* __restrict__ abuf) {
    constexpr int S = 2048, D3 = 3072, Dm = 1024, DH = 64;
    __shared__ u16 Kl[32][72];
    __shared__ u16 Vl[64][40];
    __shared__ u16 Pl[4][16][40];

    int t = threadIdx.x;
    int w = t >> 6, l = t & 63, l16 = l & 15, lh = l >> 4;
    int qt = blockIdx.x & 31;
    int bh = blockIdx.x >> 5;
    int b = bh >> 4, h = bh & 15;
    int q0 = qt * 64;
    size_t rowbase = (size_t)b * S * D3;

    int qr = q0 + w * 16 + l16;
    s16x8 qf[2];
    qf[0] = *(const s16x8*)(qkv + rowbase + (size_t)qr * D3 + h * DH + lh * 8);
    qf[1] = *(const s16x8*)(qkv + rowbase + (size_t)qr * D3 + h * DH + 32 + lh * 8);

    f32x4 O[4] = {};
    float mrow[4] = {-1e30f, -1e30f, -1e30f, -1e30f};
    float lrow[4] = {0.f, 0.f, 0.f, 0.f};

    int nch = (q0 + 64) >> 5;
    int qmax = q0 + w * 16 + 15;
    int r32 = t >> 3, c8 = (t & 7) * 8;

    for (int c = 0; c < nch; ++c) {
        int s = c * 32 + r32;
        s16x8 kk = *(const s16x8*)(qkv + rowbase + (size_t)s * D3 + Dm + h * DH + c8);
        *(s16x8*)&Kl[r32][c8] = kk;
        s16x8 vv = *(const s16x8*)(qkv + rowbase + (size_t)s * D3 + 2 * Dm + h * DH + c8);
        #pragma unroll
        for (int j = 0; j < 8; ++j) Vl[c8 + j][r32] = (u16)vv[j];
        __syncthreads();

        if (c * 32 <= qmax) {
            f32x4 s0 = {}, s1 = {};
            s16x8 kf;
            kf = *(const s16x8*)&Kl[l16][lh * 8];           s0 = mfma16(qf[0], kf, s0);
            kf = *(const s16x8*)&Kl[l16][32 + lh * 8];      s0 = mfma16(qf[1], kf, s0);
            kf = *(const s16x8*)&Kl[16 + l16][lh * 8];      s1 = mfma16(qf[0], kf, s1);
            kf = *(const s16x8*)&Kl[16 + l16][32 + lh * 8]; s1 = mfma16(qf[1], kf, s1);

            float al[4];
            #pragma unroll
            for (int i = 0; i < 4; ++i) {
                int qg = q0 + w * 16 + lh * 4 + i;
                int kg0 = c * 32 + l16;
                float v0 = s0[i] * 0.125f; if (kg0 > qg) v0 = -1e30f;
                float v1 = s1[i] * 0.125f; if (kg0 + 16 > qg) v1 = -1e30f;
                float cm = fmaxf(v0, v1);
                cm = fmaxf(cm, __shfl_xor(cm, 1));
                cm = fmaxf(cm, __shfl_xor(cm, 2));
                cm = fmaxf(cm, __shfl_xor(cm, 4));
                cm = fmaxf(cm, __shfl_xor(cm, 8));
                float mn = fmaxf(mrow[i], cm);
                float a_ = __expf(mrow[i] - mn);
                float p0 = __expf(v0 - mn);
                float p1 = __expf(v1 - mn);
                float rs = p0 + p1;
                rs += __shfl_xor(rs, 1);
                rs += __shfl_xor(rs, 2);
                rs += __shfl_xor(rs, 4);
                rs += __shfl_xor(rs, 8);
                lrow[i] = lrow[i] * a_ + rs;
                mrow[i] = mn;
                al[i] = a_;
                Pl[w][lh * 4 + i][l16] = f2b(p0);
                Pl[w][lh * 4 + i][16 + l16] = f2b(p1);
            }
            #pragma unroll
            for (int f = 0; f < 4; ++f) {
                O[f][0] *= al[0]; O[f][1] *= al[1];
                O[f][2] *= al[2]; O[f][3] *= al[3];
            }
            s16x8 pf = *(const s16x8*)&Pl[w][l16][lh * 8];
            #pragma unroll
            for (int f = 0; f < 4; ++f) {
                s16x8 vf = *(const s16x8*)&Vl[f * 16 + l16][lh * 8];
                O[f] = mfma16(pf, vf, O[f]);
            }
        }
        __syncthreads();
    }

    size_t obase = (size_t)b * S * 1024;
    #pragma unroll
    for (int i = 0; i < 4; ++i) {
        float inv = 1.f / lrow[i];
        int qg = q0 + w * 16 + lh * 4 + i;
        #pragma unroll
        for (int f = 0; f < 4; ++f)
            abuf[obase + (size_t)qg * 1024 + h * DH + f * 16 + l16] = f2b(O[f][i] * inv);
    }
}

// --------------------- residual + LayerNorm (row = 1024) --------------------
template<bool WB>
__global__ __launch_bounds__(256) void resln(const float* __restrict__ xa,
                                             const float* __restrict__ xb2,
                                             const float* __restrict__ g,
                                             const float* __restrict__ be,
                                             float* __restrict__ outf,
                                             u16* __restrict__ outb) {
    int row = blockIdx.x;
    int t = threadIdx.x;
    size_t base = (size_t)row * 1024 + t * 4;
    float4 va = *(const float4*)(xa + base);
    float4 vb = *(const float4*)(xb2 + base);
    float v0 = va.x + vb.x, v1 = va.y + vb.y, v2 = va.z + vb.z, v3 = va.w + vb.w;
    float s1 = v0 + v1 + v2 + v3;
    float s2 = v0 * v0 + v1 * v1 + v2 * v2 + v3 * v3;
    #pragma unroll
    for (int off = 32; off >= 1; off >>= 1) {
        s1 += __shfl_down(s1, off);
        s2 += __shfl_down(s2, off);
    }
    __shared__ float r1[4], r2[4];
    if ((t & 63) == 0) { r1[t >> 6] = s1; r2[t >> 6] = s2; }
    __syncthreads();
    s1 = r1[0] + r1[1] + r1[2] + r1[3];
    s2 = r2[0] + r2[1] + r2[2] + r2[3];
    float mean = s1 * (1.f / 1024.f);
    float var = fmaxf((s2 - 1024.f * mean * mean) * (1.f / 1023.f), 0.f);
    float inv = 1.f / (sqrtf(var) + 1e-6f);
    int col = t * 4;
    float y0 = g[col + 0] * ((v0 - mean) * inv) + be[col + 0];
    float y1 = g[col + 1] * ((v1 - mean) * inv) + be[col + 1];
    float y2 = g[col + 2] * ((v2 - mean) * inv) + be[col + 2];
    float y3 = g[col + 3] * ((v3 - mean) * inv) + be[col + 3];
    float4 o = {y0, y1, y2, y3};
    *(float4*)(outf + base) = o;
    if constexpr (WB) {
        u16x4 ob = {f2b(y0), f2b(y1), f2b(y2), f2b(y3)};
        *(u16x4*)(outb + base) = ob;
    }
}

// ---------------------------------------------------------------------------
extern "C" void kernel_launch(void* const* d_in, const int* in_sizes, int n_in,
                              void* d_out, int out_size, void* d_ws, size_t ws_size,
                              hipStream_t stream) {
    (void)in_sizes; (void)n_in; (void)out_size; (void)ws_size;
    const float* x       = (const float*)d_in[0];
    const float* w_attn  = (const float*)d_in[1];
    const float* b_attn  = (const float*)d_in[2];
    const float* w_aproj = (const float*)d_in[3];
    const float* b_aproj = (const float*)d_in[4];
    const float* g1      = (const float*)d_in[5];
    const float* b1      = (const float*)d_in[6];
    const float* w_fc    = (const float*)d_in[7];
    const float* b_fc    = (const float*)d_in[8];
    const float* w_mproj = (const float*)d_in[9];
    const float* b_mproj = (const float*)d_in[10];
    const float* g2      = (const float*)d_in[11];
    const float* b2      = (const float*)d_in[12];
    float* out = (float*)d_out;

    constexpr int M = 4096;           // B*S
    constexpr int D = 1024;

    // workspace arena (80 MiB), lifetimes reused
    char* ws = (char*)d_ws;
    u16*   slotA = (u16*)ws;                         // 32 MiB: qkv -> h
    char*  pB    = ws + (32u << 20);                 //  8 MiB: xb -> abuf -> nb
    char*  pC    = ws + (40u << 20);                 //  8 MiB: weight transpose
    char*  pD    = ws + (48u << 20);                 // 16 MiB: aout -> mout
    char*  pE    = ws + (64u << 20);                 // 16 MiB: n (fp32)

    u16*   xb   = (u16*)pB;
    u16*   wT   = (u16*)pC;
    u16*   qkv  = slotA;
    u16*   abuf = (u16*)pB;
    float* aout = (float*)pD;
    float* nbuf = (float*)pE;
    u16*   nb   = (u16*)pB;
    u16*   h    = slotA;
    float* mout = (float*)pD;

    dim3 blk(256);

    // 1) x -> bf16
    cvt_bf16<<<dim3(4096), blk, 0, stream>>>(x, xb, M * D / 4);

    // 2) Wattn^T ; qkv = xb @ Wattn + b_attn (bf16 out, ldc=3072)
    transpose_bf16<<<dim3(3072 / 32, 1024 / 32), blk, 0, stream>>>(w_attn, wT, 1024, 3072);
    gemm_lds<false, u16><<<dim3((M / 128) * (3072 / 128)), blk, 0, stream>>>(
        xb, wT, b_attn, qkv, M, 3072, 1024, 3072);

    // 3) causal attention -> abuf (bf16 [B,S,D])
    attn_kernel<<<dim3(1024), blk, 0, stream>>>(qkv, abuf);

    // 4) Waproj^T ; aout = abuf @ Waproj + b_aproj (fp32)
    transpose_bf16<<<dim3(1024 / 32, 1024 / 32), blk, 0, stream>>>(w_aproj, wT, 1024, 1024);
    gemm_lds<false, float><<<dim3((M / 128) * (1024 / 128)), blk, 0, stream>>>(
        abuf, wT, b_aproj, aout, M, 1024, 1024, 1024);

    // 5) n = LN(x + aout) -> nbuf fp32 + nb bf16
    resln<true><<<dim3(M), blk, 0, stream>>>(x, aout, g1, b1, nbuf, nb);

    // 6) Wfc^T ; h = gelu(nb @ Wfc + b_fc) (bf16, ldc=4096)
    transpose_bf16<<<dim3(4096 / 32, 1024 / 32), blk, 0, stream>>>(w_fc, wT, 1024, 4096);
    gemm_lds<true, u16><<<dim3((M / 128) * (4096 / 128)), blk, 0, stream>>>(
        nb, wT, b_fc, h, M, 4096, 1024, 4096);

    // 7) Wmproj^T ; mout = h @ Wmproj + b_mproj (fp32)
    transpose_bf16<<<dim3(1024 / 32, 4096 / 32), blk, 0, stream>>>(w_mproj, wT, 4096, 1024);
    gemm_lds<false, float><<<dim3((M / 128) * (1024 / 128)), blk, 0, stream>>>(
        h, wT, b_mproj, mout, M, 1024, 4096, 1024);

    // 8) out = LN(nbuf + mout) fp32
    resln<false><<<dim3(M), blk, 0, stream>>>(nbuf, mout, g2, b2, out, nullptr);
}

// Round 4
// 375.987 us; speedup vs baseline: 3.0261x; 1.3259x over previous
//
#include <hip/hip_runtime.h>
#include <type_traits>

// ---------------------------------------------------------------------------
// GPT block forward: B=2, S=2048, D=1024, H=16, DH=64
// Round 4: attention rewrite — KVBLK=64, XOR-swizzled V^T (conflict-free
// scatter), long-first causal scheduling, per-wave fragment trimming.
// GEMM/LN/transpose kernels unchanged from round 3 (m97 structure).
// ---------------------------------------------------------------------------

typedef unsigned short u16;
typedef short s16x8 __attribute__((ext_vector_type(8)));
typedef unsigned short u16x4 __attribute__((ext_vector_type(4)));
typedef float f32x4 __attribute__((ext_vector_type(4)));

__device__ __forceinline__ u16 f2b(float f) {
    union { float f; unsigned u; } x{f};
    unsigned r = x.u + 0x7FFFu + ((x.u >> 16) & 1u);  // RNE
    return (u16)(r >> 16);
}

__device__ __forceinline__ f32x4 mfma16(s16x8 a, s16x8 b, f32x4 c) {
    return __builtin_amdgcn_mfma_f32_16x16x32_bf16(a, b, c, 0, 0, 0);
}

__device__ __forceinline__ void gld_lds16(const u16* g, u16* l) {
    __builtin_amdgcn_global_load_lds(
        (const __attribute__((address_space(1))) void*)g,
        (__attribute__((address_space(3))) void*)l, 16, 0, 0);
}

// --------------------------- fp32 -> bf16 convert ---------------------------
__global__ __launch_bounds__(256) void cvt_bf16(const float* __restrict__ in,
                                                u16* __restrict__ out, int n4) {
    int i = blockIdx.x * 256 + threadIdx.x;
    if (i < n4) {
        float4 v = ((const float4*)in)[i];
        u16x4 o = {f2b(v.x), f2b(v.y), f2b(v.z), f2b(v.w)};
        ((u16x4*)out)[i] = o;
    }
}

// ------------------- transpose fp32 [K,N] -> bf16 [N,K] ---------------------
__global__ __launch_bounds__(256) void transpose_bf16(const float* __restrict__ W,
                                                      u16* __restrict__ WT,
                                                      int K, int N) {
    __shared__ float t[32][33];
    int tx = threadIdx.x & 31, ty = threadIdx.x >> 5;
    int n0 = blockIdx.x * 32, k0 = blockIdx.y * 32;
    #pragma unroll
    for (int r = ty; r < 32; r += 8)
        t[r][tx] = W[(size_t)(k0 + r) * N + n0 + tx];
    __syncthreads();
    #pragma unroll
    for (int r = ty; r < 32; r += 8)
        WT[(size_t)(n0 + r) * K + k0 + tx] = f2b(t[tx][r]);
}

// ----------------------- MFMA GEMM (m97 structure) --------------------------
template<bool GELU, typename OT>
__global__ __launch_bounds__(256) void gemm_lds(const u16* __restrict__ A,
                                                const u16* __restrict__ BT,
                                                const float* __restrict__ bias,
                                                OT* __restrict__ C,
                                                int M, int N, int K, int ldc) {
    __shared__ u16 As[128 * 32];
    __shared__ u16 Bs[128 * 32];

    int t = threadIdx.x;
    int w = t >> 6, l = t & 63, l16 = l & 15, lh = l >> 4;
    int wr = w >> 1, wc = w & 1;

    int nbm = M >> 7;
    int nwg = gridDim.x;
    int cpx = nwg >> 3;
    int id = blockIdx.x;
    int id2 = (id & 7) * cpx + (id >> 3);
    size_t m0 = (size_t)(id2 % nbm) * 128;
    size_t n0 = (size_t)(id2 / nbm) * 128;

    int rowg = t >> 2, kg = t & 3;
    const u16* Ag0 = A + (m0 + rowg) * (size_t)K + kg * 8;
    const u16* Ag1 = A + (m0 + 64 + rowg) * (size_t)K + kg * 8;
    const u16* Bg0 = BT + (n0 + rowg) * (size_t)K + kg * 8;
    const u16* Bg1 = BT + (n0 + 64 + rowg) * (size_t)K + kg * 8;
    u16* As0 = &As[w * 512];
    u16* As1 = &As[2048 + w * 512];
    u16* Bs0 = &Bs[w * 512];
    u16* Bs1 = &Bs[2048 + w * 512];

    f32x4 acc[4][4] = {};

    for (int k0 = 0; k0 < K; k0 += 32) {
        gld_lds16(Ag0 + k0, As0);
        gld_lds16(Ag1 + k0, As1);
        gld_lds16(Bg0 + k0, Bs0);
        gld_lds16(Bg1 + k0, Bs1);
        __syncthreads();

        s16x8 af[4], bf[4];
        #pragma unroll
        for (int fm = 0; fm < 4; ++fm)
            af[fm] = *(const s16x8*)&As[(wr * 64 + fm * 16 + l16) * 32 + lh * 8];
        #pragma unroll
        for (int fn = 0; fn < 4; ++fn)
            bf[fn] = *(const s16x8*)&Bs[(wc * 64 + fn * 16 + l16) * 32 + lh * 8];
        #pragma unroll
        for (int fm = 0; fm < 4; ++fm)
            #pragma unroll
            for (int fn = 0; fn < 4; ++fn)
                acc[fm][fn] = mfma16(af[fm], bf[fn], acc[fm][fn]);
        __syncthreads();
    }

    #pragma unroll
    for (int fn = 0; fn < 4; ++fn) {
        size_t col = n0 + wc * 64 + fn * 16 + l16;
        float bs = bias[col];
        #pragma unroll
        for (int fm = 0; fm < 4; ++fm) {
            size_t row0 = m0 + wr * 64 + fm * 16 + lh * 4;
            #pragma unroll
            for (int i = 0; i < 4; ++i) {
                float v = acc[fm][fn][i] + bs;
                if constexpr (GELU) {
                    float x3 = v * v * v;
                    v = 0.5f * v * (1.f + tanhf(0.7978845608f * (v + 0.044715f * x3)));
                }
                if constexpr (std::is_same<OT, u16>::value)
                    C[(row0 + i) * ldc + col] = f2b(v);
                else
                    C[(row0 + i) * ldc + col] = v;
            }
        }
    }
}

// --------------------------- causal attention -------------------------------
// qkv bf16 [B*S, 3072]; out abuf bf16 [B*S, 1024].
// Block = (qt, bh); 4 waves x 16 q-rows (QBLK=64); KVBLK=64.
// Long-first: qt = 31 - (bid>>5) so heaviest blocks dispatch first.
// K: [64][72] row-major. V^T: [64][64] with col = kv ^ (((d^(d>>3))&7)<<3)
// (conflict-free u16 scatter writes AND spread b128 reads). P: [16][72]/wave.
__global__ __launch_bounds__(256) void attn_kernel(const u16* __restrict__ qkv,
                                                   u16* __restrict__ abuf) {
    constexpr int S = 2048, D3 = 3072, Dm = 1024;
    __shared__ u16 Kl[64 * 72];
    __shared__ u16 Vt[64 * 64];
    __shared__ u16 Pl[4][16 * 72];

    int t = threadIdx.x;
    int w = t >> 6, l = t & 63, l16 = l & 15, lh = l >> 4;
    int qt = 31 - (blockIdx.x >> 5);
    int bh = blockIdx.x & 31;
    int b = bh >> 4, h = bh & 15;
    int q0 = qt * 64;
    size_t base = (size_t)b * S * D3;

    // Q fragments (A-operand): lane l -> q-row = w*16 + l16, k = lh*8(+32)
    int qr = q0 + w * 16 + l16;
    s16x8 qf[2];
    qf[0] = *(const s16x8*)(qkv + base + (size_t)qr * D3 + h * 64 + lh * 8);
    qf[1] = *(const s16x8*)(qkv + base + (size_t)qr * D3 + h * 64 + 32 + lh * 8);

    f32x4 O[4] = {};
    float mrow[4] = {-1e30f, -1e30f, -1e30f, -1e30f};
    float lrow[4] = {0.f, 0.f, 0.f, 0.f};

    // staging assignments
    int kvK = t >> 2, ckK = (t & 3) * 16;   // K: row kvK, 16 cols
    int kvV = l;                             // V: row kv = lane, cols w*16..+15
    int cv = w * 16;

    int qmax = q0 + w * 16 + 15;
    int nch = qt + 1;

    for (int c = 0; c < nch; ++c) {
        int kvb = c * 64;
        // ---- stage K [64][72]
        {
            const u16* kp = qkv + base + (size_t)(kvb + kvK) * D3 + Dm + h * 64 + ckK;
            s16x8 k0 = *(const s16x8*)kp;
            s16x8 k1 = *(const s16x8*)(kp + 8);
            *(s16x8*)&Kl[kvK * 72 + ckK] = k0;
            *(s16x8*)&Kl[kvK * 72 + ckK + 8] = k1;
        }
        // ---- stage V^T swizzled
        {
            const u16* vp = qkv + base + (size_t)(kvb + kvV) * D3 + 2 * Dm + h * 64 + cv;
            s16x8 v0 = *(const s16x8*)vp;
            s16x8 v1 = *(const s16x8*)(vp + 8);
            #pragma unroll
            for (int e = 0; e < 8; ++e) {
                int d0 = cv + e;
                int d1 = cv + 8 + e;
                int s0 = (d0 ^ (d0 >> 3)) & 7;
                int s1 = (d1 ^ (d1 >> 3)) & 7;
                Vt[d0 * 64 + (kvV ^ (s0 << 3))] = (u16)v0[e];
                Vt[d1 * 64 + (kvV ^ (s1 << 3))] = (u16)v1[e];
            }
        }
        __syncthreads();

        int rel = qmax - kvb;                 // >= 15 always (c <= qt)
        int fnmax = min(3, rel >> 4);
        int kkmax = min(1, rel >> 5);

        // ---- QK^T: sc[fn][i] = S[q=lh*4+i][kv=fn*16+l16]
        f32x4 sc[4];
        #pragma unroll
        for (int fn = 0; fn < 4; ++fn) {
            sc[fn] = f32x4{};
            if (fn <= fnmax) {
                #pragma unroll
                for (int kk = 0; kk < 2; ++kk) {
                    s16x8 kf = *(const s16x8*)&Kl[(fn * 16 + l16) * 72 + kk * 32 + lh * 8];
                    sc[fn] = mfma16(qf[kk], kf, sc[fn]);
                }
            }
        }

        // ---- online softmax (row-parallel over 16 lanes)
        float al[4];
        #pragma unroll
        for (int i = 0; i < 4; ++i) {
            int qg = q0 + w * 16 + lh * 4 + i;
            float vv[4];
            #pragma unroll
            for (int fn = 0; fn < 4; ++fn) {
                int kvg = kvb + fn * 16 + l16;
                float x = sc[fn][i] * 0.125f;
                vv[fn] = (fn <= fnmax && kvg <= qg) ? x : -1e30f;
            }
            float cm = fmaxf(fmaxf(vv[0], vv[1]), fmaxf(vv[2], vv[3]));
            cm = fmaxf(cm, __shfl_xor(cm, 1));
            cm = fmaxf(cm, __shfl_xor(cm, 2));
            cm = fmaxf(cm, __shfl_xor(cm, 4));
            cm = fmaxf(cm, __shfl_xor(cm, 8));
            float mn = fmaxf(mrow[i], cm);
            float a_ = __expf(mrow[i] - mn);
            float p0 = __expf(vv[0] - mn);
            float p1 = __expf(vv[1] - mn);
            float p2 = __expf(vv[2] - mn);
            float p3 = __expf(vv[3] - mn);
            float rs = (p0 + p1) + (p2 + p3);
            rs += __shfl_xor(rs, 1);
            rs += __shfl_xor(rs, 2);
            rs += __shfl_xor(rs, 4);
            rs += __shfl_xor(rs, 8);
            lrow[i] = lrow[i] * a_ + rs;
            mrow[i] = mn;
            al[i] = a_;
            int prow = (lh * 4 + i) * 72;
            Pl[w][prow + l16] = f2b(p0);
            Pl[w][prow + 16 + l16] = f2b(p1);
            Pl[w][prow + 32 + l16] = f2b(p2);
            Pl[w][prow + 48 + l16] = f2b(p3);
        }

        // ---- rescale O
        #pragma unroll
        for (int fd = 0; fd < 4; ++fd) {
            O[fd][0] *= al[0]; O[fd][1] *= al[1];
            O[fd][2] *= al[2]; O[fd][3] *= al[3];
        }

        // ---- PV: O[q][d] += P[q][kv] * V[kv][d]
        #pragma unroll
        for (int kk = 0; kk < 2; ++kk) {
            if (kk <= kkmax) {
                s16x8 pf = *(const s16x8*)&Pl[w][l16 * 72 + kk * 32 + lh * 8];
                #pragma unroll
                for (int fd = 0; fd < 4; ++fd) {
                    int d = fd * 16 + l16;
                    int sd = (d ^ (d >> 3)) & 7;
                    s16x8 vf = *(const s16x8*)&Vt[d * 64 + ((kk * 32 + lh * 8) ^ (sd << 3))];
                    O[fd] = mfma16(pf, vf, O[fd]);
                }
            }
        }
        __syncthreads();
    }

    size_t obase = (size_t)b * S * 1024;
    #pragma unroll
    for (int i = 0; i < 4; ++i) {
        float inv = 1.f / lrow[i];
        int qg = q0 + w * 16 + lh * 4 + i;
        #pragma unroll
        for (int fd = 0; fd < 4; ++fd)
            abuf[obase + (size_t)qg * 1024 + h * 64 + fd * 16 + l16] = f2b(O[fd][i] * inv);
    }
}

// --------------------- residual + LayerNorm (row = 1024) --------------------
template<bool WB>
__global__ __launch_bounds__(256) void resln(const float* __restrict__ xa,
                                             const float* __restrict__ xb2,
                                             const float* __restrict__ g,
                                             const float* __restrict__ be,
                                             float* __restrict__ outf,
                                             u16* __restrict__ outb) {
    int row = blockIdx.x;
    int t = threadIdx.x;
    size_t base = (size_t)row * 1024 + t * 4;
    float4 va = *(const float4*)(xa + base);
    float4 vb = *(const float4*)(xb2 + base);
    float v0 = va.x + vb.x, v1 = va.y + vb.y, v2 = va.z + vb.z, v3 = va.w + vb.w;
    float s1 = v0 + v1 + v2 + v3;
    float s2 = v0 * v0 + v1 * v1 + v2 * v2 + v3 * v3;
    #pragma unroll
    for (int off = 32; off >= 1; off >>= 1) {
        s1 += __shfl_down(s1, off);
        s2 += __shfl_down(s2, off);
    }
    __shared__ float r1[4], r2[4];
    if ((t & 63) == 0) { r1[t >> 6] = s1; r2[t >> 6] = s2; }
    __syncthreads();
    s1 = r1[0] + r1[1] + r1[2] + r1[3];
    s2 = r2[0] + r2[1] + r2[2] + r2[3];
    float mean = s1 * (1.f / 1024.f);
    float var = fmaxf((s2 - 1024.f * mean * mean) * (1.f / 1023.f), 0.f);
    float inv = 1.f / (sqrtf(var) + 1e-6f);
    int col = t * 4;
    float y0 = g[col + 0] * ((v0 - mean) * inv) + be[col + 0];
    float y1 = g[col + 1] * ((v1 - mean) * inv) + be[col + 1];
    float y2 = g[col + 2] * ((v2 - mean) * inv) + be[col + 2];
    float y3 = g[col + 3] * ((v3 - mean) * inv) + be[col + 3];
    float4 o = {y0, y1, y2, y3};
    *(float4*)(outf + base) = o;
    if constexpr (WB) {
        u16x4 ob = {f2b(y0), f2b(y1), f2b(y2), f2b(y3)};
        *(u16x4*)(outb + base) = ob;
    }
}

// ---------------------------------------------------------------------------
extern "C" void kernel_launch(void* const* d_in, const int* in_sizes, int n_in,
                              void* d_out, int out_size, void* d_ws, size_t ws_size,
                              hipStream_t stream) {
    (void)in_sizes; (void)n_in; (void)out_size; (void)ws_size;
    const float* x       = (const float*)d_in[0];
    const float* w_attn  = (const float*)d_in[1];
    const float* b_attn  = (const float*)d_in[2];
    const float* w_aproj = (const float*)d_in[3];
    const float* b_aproj = (const float*)d_in[4];
    const float* g1      = (const float*)d_in[5];
    const float* b1      = (const float*)d_in[6];
    const float* w_fc    = (const float*)d_in[7];
    const float* b_fc    = (const float*)d_in[8];
    const float* w_mproj = (const float*)d_in[9];
    const float* b_mproj = (const float*)d_in[10];
    const float* g2      = (const float*)d_in[11];
    const float* b2      = (const float*)d_in[12];
    float* out = (float*)d_out;

    constexpr int M = 4096;           // B*S
    constexpr int D = 1024;

    char* ws = (char*)d_ws;
    u16*   slotA = (u16*)ws;                         // 32 MiB: qkv -> h
    char*  pB    = ws + (32u << 20);                 //  8 MiB: xb -> abuf -> nb
    char*  pC    = ws + (40u << 20);                 //  8 MiB: weight transpose
    char*  pD    = ws + (48u << 20);                 // 16 MiB: aout -> mout
    char*  pE    = ws + (64u << 20);                 // 16 MiB: n (fp32)

    u16*   xb   = (u16*)pB;
    u16*   wT   = (u16*)pC;
    u16*   qkv  = slotA;
    u16*   abuf = (u16*)pB;
    float* aout = (float*)pD;
    float* nbuf = (float*)pE;
    u16*   nb   = (u16*)pB;
    u16*   h    = slotA;
    float* mout = (float*)pD;

    dim3 blk(256);

    cvt_bf16<<<dim3(4096), blk, 0, stream>>>(x, xb, M * D / 4);

    transpose_bf16<<<dim3(3072 / 32, 1024 / 32), blk, 0, stream>>>(w_attn, wT, 1024, 3072);
    gemm_lds<false, u16><<<dim3((M / 128) * (3072 / 128)), blk, 0, stream>>>(
        xb, wT, b_attn, qkv, M, 3072, 1024, 3072);

    attn_kernel<<<dim3(1024), blk, 0, stream>>>(qkv, abuf);

    transpose_bf16<<<dim3(1024 / 32, 1024 / 32), blk, 0, stream>>>(w_aproj, wT, 1024, 1024);
    gemm_lds<false, float><<<dim3((M / 128) * (1024 / 128)), blk, 0, stream>>>(
        abuf, wT, b_aproj, aout, M, 1024, 1024, 1024);

    resln<true><<<dim3(M), blk, 0, stream>>>(x, aout, g1, b1, nbuf, nb);

    transpose_bf16<<<dim3(4096 / 32, 1024 / 32), blk, 0, stream>>>(w_fc, wT, 1024, 4096);
    gemm_lds<true, u16><<<dim3((M / 128) * (4096 / 128)), blk, 0, stream>>>(
        nb, wT, b_fc, h, M, 4096, 1024, 4096);

    transpose_bf16<<<dim3(1024 / 32, 4096 / 32), blk, 0, stream>>>(w_mproj, wT, 4096, 1024);
    gemm_lds<false, float><<<dim3((M / 128) * (1024 / 128)), blk, 0, stream>>>(
        h, wT, b_mproj, mout, M, 1024, 4096, 1024);

    resln<false><<<dim3(M), blk, 0, stream>>>(nbuf, mout, g2, b2, out, nullptr);
}

// Round 5
// 318.410 us; speedup vs baseline: 3.5732x; 1.1808x over previous
//
#include <hip/hip_runtime.h>
#include <type_traits>

// ---------------------------------------------------------------------------
// GPT block forward: B=2, S=2048, D=1024, H=16, DH=64
// Round 5: 2-phase double-buffered GEMM (BK=64, XOR-swizzled LDS, one barrier
// per K-tile), template BN (128 for qkv/fc, 64 for aproj/mproj occupancy).
// Attention/LN/transposes unchanged from round 4.
// ---------------------------------------------------------------------------

typedef unsigned short u16;
typedef short s16x8 __attribute__((ext_vector_type(8)));
typedef unsigned short u16x4 __attribute__((ext_vector_type(4)));
typedef float f32x4 __attribute__((ext_vector_type(4)));

__device__ __forceinline__ u16 f2b(float f) {
    union { float f; unsigned u; } x{f};
    unsigned r = x.u + 0x7FFFu + ((x.u >> 16) & 1u);  // RNE
    return (u16)(r >> 16);
}

__device__ __forceinline__ f32x4 mfma16(s16x8 a, s16x8 b, f32x4 c) {
    return __builtin_amdgcn_mfma_f32_16x16x32_bf16(a, b, c, 0, 0, 0);
}

__device__ __forceinline__ void gld_lds16(const u16* g, u16* l) {
    __builtin_amdgcn_global_load_lds(
        (const __attribute__((address_space(1))) void*)g,
        (__attribute__((address_space(3))) void*)l, 16, 0, 0);
}

// --------------------------- fp32 -> bf16 convert ---------------------------
__global__ __launch_bounds__(256) void cvt_bf16(const float* __restrict__ in,
                                                u16* __restrict__ out, int n4) {
    int i = blockIdx.x * 256 + threadIdx.x;
    if (i < n4) {
        float4 v = ((const float4*)in)[i];
        u16x4 o = {f2b(v.x), f2b(v.y), f2b(v.z), f2b(v.w)};
        ((u16x4*)out)[i] = o;
    }
}

// ------------------- transpose fp32 [K,N] -> bf16 [N,K] ---------------------
__global__ __launch_bounds__(256) void transpose_bf16(const float* __restrict__ W,
                                                      u16* __restrict__ WT,
                                                      int K, int N) {
    __shared__ float t[32][33];
    int tx = threadIdx.x & 31, ty = threadIdx.x >> 5;
    int n0 = blockIdx.x * 32, k0 = blockIdx.y * 32;
    #pragma unroll
    for (int r = ty; r < 32; r += 8)
        t[r][tx] = W[(size_t)(k0 + r) * N + n0 + tx];
    __syncthreads();
    #pragma unroll
    for (int r = ty; r < 32; r += 8)
        WT[(size_t)(n0 + r) * K + k0 + tx] = f2b(t[tx][r]);
}

// ------------------ MFMA GEMM, 2-phase double-buffered ----------------------
// C[M,ldc] = A[M,K]@BT[N,K]^T + bias (bf16 in, fp32 acc). BM=128, BK=64.
// 4 waves (2x2); wave tile 64 x BN/2. LDS XOR-swizzle on stage-src + ds_read
// (involution: col ^= ((row>>2&1)<<4) ^ ((row>>3&1)<<5)) -> conflict-free.
// One __syncthreads per K-tile (vmcnt(0)+lgkmcnt(0) drain = the 2ph barrier).
template<int BN, bool GELU, typename OT>
__global__ __launch_bounds__(256) void gemm_db(const u16* __restrict__ A,
                                               const u16* __restrict__ BT,
                                               const float* __restrict__ bias,
                                               OT* __restrict__ C,
                                               int M, int N, int K, int ldc) {
    constexpr int NF = BN / 32;          // n-frags per wave
    constexpr int BNI = BN / 32;         // B staging instrs (BN*8/256)
    __shared__ u16 As[2][128 * 64];
    __shared__ u16 Bs[2][BN * 64];

    int t = threadIdx.x;
    int w = t >> 6, l = t & 63, l16 = l & 15, lh = l >> 4;
    int wr = w >> 1, wc = w & 1;

    // bijective XCD swizzle (grids all % 8 == 0), M-fastest within chunk
    int nbm = M >> 7;
    int cpx = gridDim.x >> 3;
    int id = blockIdx.x;
    int id2 = (id & 7) * cpx + (id >> 3);
    size_t m0 = (size_t)(id2 % nbm) * 128;
    size_t n0 = (size_t)(id2 / nbm) * BN;

    // staging: granule g = row*8 + gc (16B); instr j covers rows j*32..+31.
    // pre-swizzled source column so that linear LDS dest + swizzled read agree.
    int rowA = t >> 3;
    int gc = t & 7;
    int gc2 = gc ^ (((rowA >> 2) & 1) << 1) ^ (((rowA >> 3) & 1) << 2);
    const u16* Ag = A + (m0 + rowA) * (size_t)K + gc2 * 8;
    const u16* Bg = BT + (n0 + rowA) * (size_t)K + gc2 * 8;
    int wbase = w * 512;                 // per-wave linear LDS base (u16)

    f32x4 acc[4][NF] = {};
    // ds_read col-XOR depends only on l16 bits 2,3 (same for A and B frags)
    int cxor = (((l16 >> 2) & 1) << 4) ^ (((l16 >> 3) & 1) << 5);

    // prologue: stage tile 0 into buf 0
    #pragma unroll
    for (int j = 0; j < 4; ++j)
        gld_lds16(Ag + (size_t)j * 32 * K, &As[0][j * 2048 + wbase]);
    #pragma unroll
    for (int j = 0; j < BNI; ++j)
        gld_lds16(Bg + (size_t)j * 32 * K, &Bs[0][j * 2048 + wbase]);
    __syncthreads();

    int cur = 0;
    for (int k0 = 0; k0 < K; k0 += 64) {
        if (k0 + 64 < K) {               // stage next tile into buf cur^1
            const u16* Ap = Ag + k0 + 64;
            #pragma unroll
            for (int j = 0; j < 4; ++j)
                gld_lds16(Ap + (size_t)j * 32 * K, &As[cur ^ 1][j * 2048 + wbase]);
            const u16* Bp = Bg + k0 + 64;
            #pragma unroll
            for (int j = 0; j < BNI; ++j)
                gld_lds16(Bp + (size_t)j * 32 * K, &Bs[cur ^ 1][j * 2048 + wbase]);
        }
        __builtin_amdgcn_s_setprio(1);
        #pragma unroll
        for (int ks = 0; ks < 2; ++ks) {
            s16x8 af[4], bf[NF];
            #pragma unroll
            for (int fm = 0; fm < 4; ++fm) {
                int row = wr * 64 + fm * 16 + l16;
                int col = (ks * 32 + lh * 8) ^ cxor;
                af[fm] = *(const s16x8*)&As[cur][row * 64 + col];
            }
            #pragma unroll
            for (int fn = 0; fn < NF; ++fn) {
                int row = wc * (BN / 2) + fn * 16 + l16;
                int col = (ks * 32 + lh * 8) ^ cxor;
                bf[fn] = *(const s16x8*)&Bs[cur][row * 64 + col];
            }
            #pragma unroll
            for (int fm = 0; fm < 4; ++fm)
                #pragma unroll
                for (int fn = 0; fn < NF; ++fn)
                    acc[fm][fn] = mfma16(af[fm], bf[fn], acc[fm][fn]);
        }
        __builtin_amdgcn_s_setprio(0);
        __syncthreads();                 // vmcnt(0)+lgkmcnt(0) drain + barrier
        cur ^= 1;
    }

    #pragma unroll
    for (int fn = 0; fn < NF; ++fn) {
        size_t col = n0 + wc * (BN / 2) + fn * 16 + l16;
        float bs = bias[col];
        #pragma unroll
        for (int fm = 0; fm < 4; ++fm) {
            size_t row0 = m0 + wr * 64 + fm * 16 + lh * 4;
            #pragma unroll
            for (int i = 0; i < 4; ++i) {
                float v = acc[fm][fn][i] + bs;
                if constexpr (GELU) {
                    float x3 = v * v * v;
                    v = 0.5f * v * (1.f + tanhf(0.7978845608f * (v + 0.044715f * x3)));
                }
                if constexpr (std::is_same<OT, u16>::value)
                    C[(row0 + i) * ldc + col] = f2b(v);
                else
                    C[(row0 + i) * ldc + col] = v;
            }
        }
    }
}

// --------------------------- causal attention -------------------------------
__global__ __launch_bounds__(256) void attn_kernel(const u16* __restrict__ qkv,
                                                   u16* __restrict__ abuf) {
    constexpr int S = 2048, D3 = 3072, Dm = 1024;
    __shared__ u16 Kl[64 * 72];
    __shared__ u16 Vt[64 * 64];
    __shared__ u16 Pl[4][16 * 72];

    int t = threadIdx.x;
    int w = t >> 6, l = t & 63, l16 = l & 15, lh = l >> 4;
    int qt = 31 - (blockIdx.x >> 5);
    int bh = blockIdx.x & 31;
    int b = bh >> 4, h = bh & 15;
    int q0 = qt * 64;
    size_t base = (size_t)b * S * D3;

    int qr = q0 + w * 16 + l16;
    s16x8 qf[2];
    qf[0] = *(const s16x8*)(qkv + base + (size_t)qr * D3 + h * 64 + lh * 8);
    qf[1] = *(const s16x8*)(qkv + base + (size_t)qr * D3 + h * 64 + 32 + lh * 8);

    f32x4 O[4] = {};
    float mrow[4] = {-1e30f, -1e30f, -1e30f, -1e30f};
    float lrow[4] = {0.f, 0.f, 0.f, 0.f};

    int kvK = t >> 2, ckK = (t & 3) * 16;
    int kvV = l;
    int cv = w * 16;

    int qmax = q0 + w * 16 + 15;
    int nch = qt + 1;

    for (int c = 0; c < nch; ++c) {
        int kvb = c * 64;
        {
            const u16* kp = qkv + base + (size_t)(kvb + kvK) * D3 + Dm + h * 64 + ckK;
            s16x8 k0 = *(const s16x8*)kp;
            s16x8 k1 = *(const s16x8*)(kp + 8);
            *(s16x8*)&Kl[kvK * 72 + ckK] = k0;
            *(s16x8*)&Kl[kvK * 72 + ckK + 8] = k1;
        }
        {
            const u16* vp = qkv + base + (size_t)(kvb + kvV) * D3 + 2 * Dm + h * 64 + cv;
            s16x8 v0 = *(const s16x8*)vp;
            s16x8 v1 = *(const s16x8*)(vp + 8);
            #pragma unroll
            for (int e = 0; e < 8; ++e) {
                int d0 = cv + e;
                int d1 = cv + 8 + e;
                int s0 = (d0 ^ (d0 >> 3)) & 7;
                int s1 = (d1 ^ (d1 >> 3)) & 7;
                Vt[d0 * 64 + (kvV ^ (s0 << 3))] = (u16)v0[e];
                Vt[d1 * 64 + (kvV ^ (s1 << 3))] = (u16)v1[e];
            }
        }
        __syncthreads();

        int rel = qmax - kvb;
        int fnmax = min(3, rel >> 4);
        int kkmax = min(1, rel >> 5);

        f32x4 sc[4];
        #pragma unroll
        for (int fn = 0; fn < 4; ++fn) {
            sc[fn] = f32x4{};
            if (fn <= fnmax) {
                #pragma unroll
                for (int kk = 0; kk < 2; ++kk) {
                    s16x8 kf = *(const s16x8*)&Kl[(fn * 16 + l16) * 72 + kk * 32 + lh * 8];
                    sc[fn] = mfma16(qf[kk], kf, sc[fn]);
                }
            }
        }

        float al[4];
        #pragma unroll
        for (int i = 0; i < 4; ++i) {
            int qg = q0 + w * 16 + lh * 4 + i;
            float vv[4];
            #pragma unroll
            for (int fn = 0; fn < 4; ++fn) {
                int kvg = kvb + fn * 16 + l16;
                float x = sc[fn][i] * 0.125f;
                vv[fn] = (fn <= fnmax && kvg <= qg) ? x : -1e30f;
            }
            float cm = fmaxf(fmaxf(vv[0], vv[1]), fmaxf(vv[2], vv[3]));
            cm = fmaxf(cm, __shfl_xor(cm, 1));
            cm = fmaxf(cm, __shfl_xor(cm, 2));
            cm = fmaxf(cm, __shfl_xor(cm, 4));
            cm = fmaxf(cm, __shfl_xor(cm, 8));
            float mn = fmaxf(mrow[i], cm);
            float a_ = __expf(mrow[i] - mn);
            float p0 = __expf(vv[0] - mn);
            float p1 = __expf(vv[1] - mn);
            float p2 = __expf(vv[2] - mn);
            float p3 = __expf(vv[3] - mn);
            float rs = (p0 + p1) + (p2 + p3);
            rs += __shfl_xor(rs, 1);
            rs += __shfl_xor(rs, 2);
            rs += __shfl_xor(rs, 4);
            rs += __shfl_xor(rs, 8);
            lrow[i] = lrow[i] * a_ + rs;
            mrow[i] = mn;
            al[i] = a_;
            int prow = (lh * 4 + i) * 72;
            Pl[w][prow + l16] = f2b(p0);
            Pl[w][prow + 16 + l16] = f2b(p1);
            Pl[w][prow + 32 + l16] = f2b(p2);
            Pl[w][prow + 48 + l16] = f2b(p3);
        }

        #pragma unroll
        for (int fd = 0; fd < 4; ++fd) {
            O[fd][0] *= al[0]; O[fd][1] *= al[1];
            O[fd][2] *= al[2]; O[fd][3] *= al[3];
        }

        #pragma unroll
        for (int kk = 0; kk < 2; ++kk) {
            if (kk <= kkmax) {
                s16x8 pf = *(const s16x8*)&Pl[w][l16 * 72 + kk * 32 + lh * 8];
                #pragma unroll
                for (int fd = 0; fd < 4; ++fd) {
                    int d = fd * 16 + l16;
                    int sd = (d ^ (d >> 3)) & 7;
                    s16x8 vf = *(const s16x8*)&Vt[d * 64 + ((kk * 32 + lh * 8) ^ (sd << 3))];
                    O[fd] = mfma16(pf, vf, O[fd]);
                }
            }
        }
        __syncthreads();
    }

    size_t obase = (size_t)b * S * 1024;
    #pragma unroll
    for (int i = 0; i < 4; ++i) {
        float inv = 1.f / lrow[i];
        int qg = q0 + w * 16 + lh * 4 + i;
        #pragma unroll
        for (int fd = 0; fd < 4; ++fd)
            abuf[obase + (size_t)qg * 1024 + h * 64 + fd * 16 + l16] = f2b(O[fd][i] * inv);
    }
}

// --------------------- residual + LayerNorm (row = 1024) --------------------
template<bool WB>
__global__ __launch_bounds__(256) void resln(const float* __restrict__ xa,
                                             const float* __restrict__ xb2,
                                             const float* __restrict__ g,
                                             const float* __restrict__ be,
                                             float* __restrict__ outf,
                                             u16* __restrict__ outb) {
    int row = blockIdx.x;
    int t = threadIdx.x;
    size_t base = (size_t)row * 1024 + t * 4;
    float4 va = *(const float4*)(xa + base);
    float4 vb = *(const float4*)(xb2 + base);
    float v0 = va.x + vb.x, v1 = va.y + vb.y, v2 = va.z + vb.z, v3 = va.w + vb.w;
    float s1 = v0 + v1 + v2 + v3;
    float s2 = v0 * v0 + v1 * v1 + v2 * v2 + v3 * v3;
    #pragma unroll
    for (int off = 32; off >= 1; off >>= 1) {
        s1 += __shfl_down(s1, off);
        s2 += __shfl_down(s2, off);
    }
    __shared__ float r1[4], r2[4];
    if ((t & 63) == 0) { r1[t >> 6] = s1; r2[t >> 6] = s2; }
    __syncthreads();
    s1 = r1[0] + r1[1] + r1[2] + r1[3];
    s2 = r2[0] + r2[1] + r2[2] + r2[3];
    float mean = s1 * (1.f / 1024.f);
    float var = fmaxf((s2 - 1024.f * mean * mean) * (1.f / 1023.f), 0.f);
    float inv = 1.f / (sqrtf(var) + 1e-6f);
    int col = t * 4;
    float y0 = g[col + 0] * ((v0 - mean) * inv) + be[col + 0];
    float y1 = g[col + 1] * ((v1 - mean) * inv) + be[col + 1];
    float y2 = g[col + 2] * ((v2 - mean) * inv) + be[col + 2];
    float y3 = g[col + 3] * ((v3 - mean) * inv) + be[col + 3];
    float4 o = {y0, y1, y2, y3};
    *(float4*)(outf + base) = o;
    if constexpr (WB) {
        u16x4 ob = {f2b(y0), f2b(y1), f2b(y2), f2b(y3)};
        *(u16x4*)(outb + base) = ob;
    }
}

// ---------------------------------------------------------------------------
extern "C" void kernel_launch(void* const* d_in, const int* in_sizes, int n_in,
                              void* d_out, int out_size, void* d_ws, size_t ws_size,
                              hipStream_t stream) {
    (void)in_sizes; (void)n_in; (void)out_size; (void)ws_size;
    const float* x       = (const float*)d_in[0];
    const float* w_attn  = (const float*)d_in[1];
    const float* b_attn  = (const float*)d_in[2];
    const float* w_aproj = (const float*)d_in[3];
    const float* b_aproj = (const float*)d_in[4];
    const float* g1      = (const float*)d_in[5];
    const float* b1      = (const float*)d_in[6];
    const float* w_fc    = (const float*)d_in[7];
    const float* b_fc    = (const float*)d_in[8];
    const float* w_mproj = (const float*)d_in[9];
    const float* b_mproj = (const float*)d_in[10];
    const float* g2      = (const float*)d_in[11];
    const float* b2      = (const float*)d_in[12];
    float* out = (float*)d_out;

    constexpr int M = 4096;           // B*S
    constexpr int D = 1024;

    char* ws = (char*)d_ws;
    u16*   slotA = (u16*)ws;                         // 32 MiB: qkv -> h
    char*  pB    = ws + (32u << 20);                 //  8 MiB: xb -> abuf -> nb
    char*  pC    = ws + (40u << 20);                 //  8 MiB: weight transpose
    char*  pD    = ws + (48u << 20);                 // 16 MiB: aout -> mout
    char*  pE    = ws + (64u << 20);                 // 16 MiB: n (fp32)

    u16*   xb   = (u16*)pB;
    u16*   wT   = (u16*)pC;
    u16*   qkv  = slotA;
    u16*   abuf = (u16*)pB;
    float* aout = (float*)pD;
    float* nbuf = (float*)pE;
    u16*   nb   = (u16*)pB;
    u16*   h    = slotA;
    float* mout = (float*)pD;

    dim3 blk(256);

    cvt_bf16<<<dim3(4096), blk, 0, stream>>>(x, xb, M * D / 4);

    transpose_bf16<<<dim3(3072 / 32, 1024 / 32), blk, 0, stream>>>(w_attn, wT, 1024, 3072);
    gemm_db<128, false, u16><<<dim3((M / 128) * (3072 / 128)), blk, 0, stream>>>(
        xb, wT, b_attn, qkv, M, 3072, 1024, 3072);

    attn_kernel<<<dim3(1024), blk, 0, stream>>>(qkv, abuf);

    transpose_bf16<<<dim3(1024 / 32, 1024 / 32), blk, 0, stream>>>(w_aproj, wT, 1024, 1024);
    gemm_db<64, false, float><<<dim3((M / 128) * (1024 / 64)), blk, 0, stream>>>(
        abuf, wT, b_aproj, aout, M, 1024, 1024, 1024);

    resln<true><<<dim3(M), blk, 0, stream>>>(x, aout, g1, b1, nbuf, nb);

    transpose_bf16<<<dim3(4096 / 32, 1024 / 32), blk, 0, stream>>>(w_fc, wT, 1024, 4096);
    gemm_db<128, true, u16><<<dim3((M / 128) * (4096 / 128)), blk, 0, stream>>>(
        nb, wT, b_fc, h, M, 4096, 1024, 4096);

    transpose_bf16<<<dim3(1024 / 32, 4096 / 32), blk, 0, stream>>>(w_mproj, wT, 4096, 1024);
    gemm_db<64, false, float><<<dim3((M / 128) * (1024 / 64)), blk, 0, stream>>>(
        h, wT, b_mproj, mout, M, 1024, 4096, 1024);

    resln<false><<<dim3(M), blk, 0, stream>>>(nbuf, mout, g2, b2, out, nullptr);
}

// Round 7
// 314.203 us; speedup vs baseline: 3.6211x; 1.0134x over previous
//
#include <hip/hip_runtime.h>
#include <type_traits>

// ---------------------------------------------------------------------------
// GPT block forward: B=2, S=2048, D=1024, H=16, DH=64
// Round 7: round-6 swapped-QK^T attention with the P half-exchange fixed
// (shfl_xor(32) + select instead of mis-directed v_permlane32_swap).
// GEMM/LN unchanged from round 5.
// ---------------------------------------------------------------------------

typedef unsigned short u16;
typedef short s16x8 __attribute__((ext_vector_type(8)));
typedef unsigned short u16x4 __attribute__((ext_vector_type(4)));
typedef float f32x4 __attribute__((ext_vector_type(4)));
typedef float f32x16 __attribute__((ext_vector_type(16)));

__device__ __forceinline__ u16 f2b(float f) {
    union { float f; unsigned u; } x{f};
    unsigned r = x.u + 0x7FFFu + ((x.u >> 16) & 1u);  // RNE
    return (u16)(r >> 16);
}

__device__ __forceinline__ f32x4 mfma16(s16x8 a, s16x8 b, f32x4 c) {
    return __builtin_amdgcn_mfma_f32_16x16x32_bf16(a, b, c, 0, 0, 0);
}

__device__ __forceinline__ f32x16 mfma32(s16x8 a, s16x8 b, f32x16 c) {
    return __builtin_amdgcn_mfma_f32_32x32x16_bf16(a, b, c, 0, 0, 0);
}

__device__ __forceinline__ int cvtpk(float a, float b) {
    int r;
    asm("v_cvt_pk_bf16_f32 %0, %1, %2" : "=v"(r) : "v"(a), "v"(b));
    return r;
}

__device__ __forceinline__ void gld_lds16(const u16* g, u16* l) {
    __builtin_amdgcn_global_load_lds(
        (const __attribute__((address_space(1))) void*)g,
        (__attribute__((address_space(3))) void*)l, 16, 0, 0);
}

// --------------------------- fp32 -> bf16 convert ---------------------------
__global__ __launch_bounds__(256) void cvt_bf16(const float* __restrict__ in,
                                                u16* __restrict__ out, int n4) {
    int i = blockIdx.x * 256 + threadIdx.x;
    if (i < n4) {
        float4 v = ((const float4*)in)[i];
        u16x4 o = {f2b(v.x), f2b(v.y), f2b(v.z), f2b(v.w)};
        ((u16x4*)out)[i] = o;
    }
}

// ------------------- transpose fp32 [K,N] -> bf16 [N,K] ---------------------
__global__ __launch_bounds__(256) void transpose_bf16(const float* __restrict__ W,
                                                      u16* __restrict__ WT,
                                                      int K, int N) {
    __shared__ float t[32][33];
    int tx = threadIdx.x & 31, ty = threadIdx.x >> 5;
    int n0 = blockIdx.x * 32, k0 = blockIdx.y * 32;
    #pragma unroll
    for (int r = ty; r < 32; r += 8)
        t[r][tx] = W[(size_t)(k0 + r) * N + n0 + tx];
    __syncthreads();
    #pragma unroll
    for (int r = ty; r < 32; r += 8)
        WT[(size_t)(n0 + r) * K + k0 + tx] = f2b(t[tx][r]);
}

// ------------------ MFMA GEMM, 2-phase double-buffered ----------------------
template<int BN, bool GELU, typename OT>
__global__ __launch_bounds__(256) void gemm_db(const u16* __restrict__ A,
                                               const u16* __restrict__ BT,
                                               const float* __restrict__ bias,
                                               OT* __restrict__ C,
                                               int M, int N, int K, int ldc) {
    constexpr int NF = BN / 32;
    constexpr int BNI = BN / 32;
    __shared__ u16 As[2][128 * 64];
    __shared__ u16 Bs[2][BN * 64];

    int t = threadIdx.x;
    int w = t >> 6, l = t & 63, l16 = l & 15, lh = l >> 4;
    int wr = w >> 1, wc = w & 1;

    int nbm = M >> 7;
    int cpx = gridDim.x >> 3;
    int id = blockIdx.x;
    int id2 = (id & 7) * cpx + (id >> 3);
    size_t m0 = (size_t)(id2 % nbm) * 128;
    size_t n0 = (size_t)(id2 / nbm) * BN;

    int rowA = t >> 3;
    int gc = t & 7;
    int gc2 = gc ^ (((rowA >> 2) & 1) << 1) ^ (((rowA >> 3) & 1) << 2);
    const u16* Ag = A + (m0 + rowA) * (size_t)K + gc2 * 8;
    const u16* Bg = BT + (n0 + rowA) * (size_t)K + gc2 * 8;
    int wbase = w * 512;

    f32x4 acc[4][NF] = {};
    int cxor = (((l16 >> 2) & 1) << 4) ^ (((l16 >> 3) & 1) << 5);

    #pragma unroll
    for (int j = 0; j < 4; ++j)
        gld_lds16(Ag + (size_t)j * 32 * K, &As[0][j * 2048 + wbase]);
    #pragma unroll
    for (int j = 0; j < BNI; ++j)
        gld_lds16(Bg + (size_t)j * 32 * K, &Bs[0][j * 2048 + wbase]);
    __syncthreads();

    int cur = 0;
    for (int k0 = 0; k0 < K; k0 += 64) {
        if (k0 + 64 < K) {
            const u16* Ap = Ag + k0 + 64;
            #pragma unroll
            for (int j = 0; j < 4; ++j)
                gld_lds16(Ap + (size_t)j * 32 * K, &As[cur ^ 1][j * 2048 + wbase]);
            const u16* Bp = Bg + k0 + 64;
            #pragma unroll
            for (int j = 0; j < BNI; ++j)
                gld_lds16(Bp + (size_t)j * 32 * K, &Bs[cur ^ 1][j * 2048 + wbase]);
        }
        __builtin_amdgcn_s_setprio(1);
        #pragma unroll
        for (int ks = 0; ks < 2; ++ks) {
            s16x8 af[4], bf[NF];
            #pragma unroll
            for (int fm = 0; fm < 4; ++fm) {
                int row = wr * 64 + fm * 16 + l16;
                int col = (ks * 32 + lh * 8) ^ cxor;
                af[fm] = *(const s16x8*)&As[cur][row * 64 + col];
            }
            #pragma unroll
            for (int fn = 0; fn < NF; ++fn) {
                int row = wc * (BN / 2) + fn * 16 + l16;
                int col = (ks * 32 + lh * 8) ^ cxor;
                bf[fn] = *(const s16x8*)&Bs[cur][row * 64 + col];
            }
            #pragma unroll
            for (int fm = 0; fm < 4; ++fm)
                #pragma unroll
                for (int fn = 0; fn < NF; ++fn)
                    acc[fm][fn] = mfma16(af[fm], bf[fn], acc[fm][fn]);
        }
        __builtin_amdgcn_s_setprio(0);
        __syncthreads();
        cur ^= 1;
    }

    #pragma unroll
    for (int fn = 0; fn < NF; ++fn) {
        size_t col = n0 + wc * (BN / 2) + fn * 16 + l16;
        float bs = bias[col];
        #pragma unroll
        for (int fm = 0; fm < 4; ++fm) {
            size_t row0 = m0 + wr * 64 + fm * 16 + lh * 4;
            #pragma unroll
            for (int i = 0; i < 4; ++i) {
                float v = acc[fm][fn][i] + bs;
                if constexpr (GELU) {
                    float x3 = v * v * v;
                    v = 0.5f * v * (1.f + tanhf(0.7978845608f * (v + 0.044715f * x3)));
                }
                if constexpr (std::is_same<OT, u16>::value)
                    C[(row0 + i) * ldc + col] = f2b(v);
                else
                    C[(row0 + i) * ldc + col] = v;
            }
        }
    }
}

// --------------------------- causal attention -------------------------------
// Swapped-QK^T 32x32 structure. Block = 4 waves x 32 q-rows (QBLK=128);
// stage 64 kv (K granule-swizzled, V^T u16-swizzled), compute 2x 32-kv tiles.
// Lane owns q = l&31; softmax lane-local + one shfl_xor(32).
// P->PV A-frag exchange between lane pairs (l, l+32) via shfl_xor(32):
//   needed: hi=0 lane kv 0..7 = {own p0-3, partner p0-3}
//           hi=1 lane kv 8..15 = {partner p4-7, own p4-7}
// C/D map: col=l&31, row=crow(reg,hi)=(reg&3)+8*(reg>>2)+4*hi  [m74/m101].
__global__ __launch_bounds__(256) void attn_kernel(const u16* __restrict__ qkv,
                                                   u16* __restrict__ abuf) {
    constexpr int S = 2048, D3 = 3072, Dm = 1024;
    __shared__ u16 Kl[64 * 64];
    __shared__ u16 Vt[64 * 64];

    int t = threadIdx.x;
    int w = t >> 6, l = t & 63;
    int l32 = l & 31, hi = l >> 5;
    int qt = 15 - (int)(blockIdx.x >> 5);      // long-first
    int bh = blockIdx.x & 31;
    int b = bh >> 4, h = bh & 15;
    int qb = qt * 128 + w * 32;                // wave's q base
    size_t base = (size_t)b * S * D3;

    // Q b-frags: lane l -> q-row qb+l32, dh = kk*16 + hi*8 .. +7
    s16x8 qf[4];
    const u16* qp = qkv + base + (size_t)(qb + l32) * D3 + h * 64 + hi * 8;
    #pragma unroll
    for (int kk = 0; kk < 4; ++kk)
        qf[kk] = *(const s16x8*)(qp + kk * 16);

    f32x16 O0 = {}, O1 = {};
    float m = -1e30f, lr = 0.f;
    constexpr float cexp = 0.18033688011112042f;   // 0.125 * log2(e)
    constexpr float THR = 64.0f;                    // = 8 in scaled units

    int rK = t >> 2, gK = t & 3;
    int sK0 = gK ^ (rK & 7), sK1 = (gK + 4) ^ (rK & 7);
    const u16* kgp = qkv + base + (size_t)rK * D3 + Dm + h * 64;
    int cv = w * 16;

    int nst = 2 * (qt + 1);
    for (int sc = 0; sc < nst; ++sc) {
        int kvb = sc * 64;
        if (sc) __syncthreads();
        {   // stage K [64 kv][64 dh]: phys granule g holds logical g^(r&7)
            const u16* kp = kgp + (size_t)kvb * D3;
            s16x8 a0 = *(const s16x8*)(kp + sK0 * 8);
            s16x8 a1 = *(const s16x8*)(kp + sK1 * 8);
            *(s16x8*)&Kl[rK * 64 + gK * 8] = a0;
            *(s16x8*)&Kl[rK * 64 + (gK + 4) * 8] = a1;
        }
        {   // stage V^T [64 d][64 kv], u16 col kv stored at kv^((d&7)<<3)
            const u16* vp = qkv + base + (size_t)(kvb + l) * D3 + 2 * Dm + h * 64 + cv;
            s16x8 v0 = *(const s16x8*)vp;
            s16x8 v1 = *(const s16x8*)(vp + 8);
            #pragma unroll
            for (int e = 0; e < 8; ++e) {
                int d0 = cv + e, d1 = cv + 8 + e;
                Vt[d0 * 64 + (l ^ ((d0 & 7) << 3))] = (u16)v0[e];
                Vt[d1 * 64 + (l ^ ((d1 & 7) << 3))] = (u16)v1[e];
            }
        }
        __syncthreads();

        #pragma unroll
        for (int ti = 0; ti < 2; ++ti) {
            int kvt = kvb + ti * 32;
            if (kvt > qb) continue;                 // wave-uniform trim
            bool diag = (kvt == qb);

            // QK^T swapped: D[m=kv][n=q]; lane: q=l32, kv=crow(reg,hi)
            f32x16 sa = {};
            #pragma unroll
            for (int kk = 0; kk < 4; ++kk) {
                int r = ti * 32 + l32;
                s16x8 kf = *(const s16x8*)&Kl[r * 64 + (((2 * kk + hi) ^ (r & 7)) * 8)];
                sa = mfma32(kf, qf[kk], sa);
            }

            // mask (diagonal tile only) + row max
            float p[16];
            float mx = -1e30f;
            #pragma unroll
            for (int reg = 0; reg < 16; ++reg) {
                int kvloc = (reg & 3) + 8 * (reg >> 2) + 4 * hi;
                float s = sa[reg];
                if (diag && kvloc > l32) s = -1e30f;
                p[reg] = s;
                mx = fmaxf(mx, s);
            }
            mx = fmaxf(mx, __shfl_xor(mx, 32));

            bool skip = __all(mx <= m + THR);       // defer-max (T13)
            if (!skip) {
                float mn = fmaxf(m, mx);
                float a_ = exp2f(cexp * (m - mn));
                m = mn;
                #pragma unroll
                for (int reg = 0; reg < 16; ++reg) {
                    int src = (reg & 3) + 8 * (reg >> 2) + 4 * hi;
                    float aq = __shfl(a_, src);     // a for q-row = crow
                    O0[reg] *= aq;
                    O1[reg] *= aq;
                }
                lr *= a_;
            }
            float rs = 0.f;
            #pragma unroll
            for (int reg = 0; reg < 16; ++reg) {
                p[reg] = exp2f(cexp * (p[reg] - m));
                rs += p[reg];
            }
            rs += __shfl_xor(rs, 32);
            lr += rs;

            // P -> bf16 PV A-frags (exchange via shfl_xor(32), derived above)
            s16x8 pa[2];
            #pragma unroll
            for (int kk = 0; kk < 2; ++kk) {
                int pk01 = cvtpk(p[kk * 8 + 0], p[kk * 8 + 1]);
                int pk23 = cvtpk(p[kk * 8 + 2], p[kk * 8 + 3]);
                int pk45 = cvtpk(p[kk * 8 + 4], p[kk * 8 + 5]);
                int pk67 = cvtpk(p[kk * 8 + 6], p[kk * 8 + 7]);
                int sx01 = __shfl_xor(pk01, 32);
                int sx23 = __shfl_xor(pk23, 32);
                int sx45 = __shfl_xor(pk45, 32);
                int sx67 = __shfl_xor(pk67, 32);
                union { int i[4]; s16x8 v; } u;
                u.i[0] = hi ? sx45 : pk01;   // e0,e1
                u.i[1] = hi ? sx67 : pk23;   // e2,e3
                u.i[2] = hi ? pk45 : sx01;   // e4,e5
                u.i[3] = hi ? pk67 : sx23;   // e6,e7
                pa[kk] = u.v;
            }

            // PV: O[q][d] += P[q][kv] V[kv][d]; B-frag rows d = dt*32+l32
            #pragma unroll
            for (int kk = 0; kk < 2; ++kk) {
                int d0 = l32;
                s16x8 vb0 = *(const s16x8*)&Vt[d0 * 64 + (((ti * 4 + kk * 2 + hi) ^ (d0 & 7)) * 8)];
                O0 = mfma32(pa[kk], vb0, O0);
                int d1 = 32 + l32;
                s16x8 vb1 = *(const s16x8*)&Vt[d1 * 64 + (((ti * 4 + kk * 2 + hi) ^ (d1 & 7)) * 8)];
                O1 = mfma32(pa[kk], vb1, O1);
            }
        }
    }

    // epilogue: lane holds O[q=crow(reg,hi)][d=dt*32+l32]; 1/l via shfl
    float invl = 1.f / lr;
    size_t obase = (size_t)b * S * 1024 + h * 64;
    #pragma unroll
    for (int reg = 0; reg < 16; ++reg) {
        int src = (reg & 3) + 8 * (reg >> 2) + 4 * hi;
        float iq = __shfl(invl, src);
        size_t row = obase + (size_t)(qb + src) * 1024;
        abuf[row + l32] = f2b(O0[reg] * iq);
        abuf[row + 32 + l32] = f2b(O1[reg] * iq);
    }
}

// --------------------- residual + LayerNorm (row = 1024) --------------------
template<bool WB>
__global__ __launch_bounds__(256) void resln(const float* __restrict__ xa,
                                             const float* __restrict__ xb2,
                                             const float* __restrict__ g,
                                             const float* __restrict__ be,
                                             float* __restrict__ outf,
                                             u16* __restrict__ outb) {
    int row = blockIdx.x;
    int t = threadIdx.x;
    size_t base = (size_t)row * 1024 + t * 4;
    float4 va = *(const float4*)(xa + base);
    float4 vb = *(const float4*)(xb2 + base);
    float v0 = va.x + vb.x, v1 = va.y + vb.y, v2 = va.z + vb.z, v3 = va.w + vb.w;
    float s1 = v0 + v1 + v2 + v3;
    float s2 = v0 * v0 + v1 * v1 + v2 * v2 + v3 * v3;
    #pragma unroll
    for (int off = 32; off >= 1; off >>= 1) {
        s1 += __shfl_down(s1, off);
        s2 += __shfl_down(s2, off);
    }
    __shared__ float r1[4], r2[4];
    if ((t & 63) == 0) { r1[t >> 6] = s1; r2[t >> 6] = s2; }
    __syncthreads();
    s1 = r1[0] + r1[1] + r1[2] + r1[3];
    s2 = r2[0] + r2[1] + r2[2] + r2[3];
    float mean = s1 * (1.f / 1024.f);
    float var = fmaxf((s2 - 1024.f * mean * mean) * (1.f / 1023.f), 0.f);
    float inv = 1.f / (sqrtf(var) + 1e-6f);
    int col = t * 4;
    float y0 = g[col + 0] * ((v0 - mean) * inv) + be[col + 0];
    float y1 = g[col + 1] * ((v1 - mean) * inv) + be[col + 1];
    float y2 = g[col + 2] * ((v2 - mean) * inv) + be[col + 2];
    float y3 = g[col + 3] * ((v3 - mean) * inv) + be[col + 3];
    float4 o = {y0, y1, y2, y3};
    *(float4*)(outf + base) = o;
    if constexpr (WB) {
        u16x4 ob = {f2b(y0), f2b(y1), f2b(y2), f2b(y3)};
        *(u16x4*)(outb + base) = ob;
    }
}

// ---------------------------------------------------------------------------
extern "C" void kernel_launch(void* const* d_in, const int* in_sizes, int n_in,
                              void* d_out, int out_size, void* d_ws, size_t ws_size,
                              hipStream_t stream) {
    (void)in_sizes; (void)n_in; (void)out_size; (void)ws_size;
    const float* x       = (const float*)d_in[0];
    const float* w_attn  = (const float*)d_in[1];
    const float* b_attn  = (const float*)d_in[2];
    const float* w_aproj = (const float*)d_in[3];
    const float* b_aproj = (const float*)d_in[4];
    const float* g1      = (const float*)d_in[5];
    const float* b1      = (const float*)d_in[6];
    const float* w_fc    = (const float*)d_in[7];
    const float* b_fc    = (const float*)d_in[8];
    const float* w_mproj = (const float*)d_in[9];
    const float* b_mproj = (const float*)d_in[10];
    const float* g2      = (const float*)d_in[11];
    const float* b2      = (const float*)d_in[12];
    float* out = (float*)d_out;

    constexpr int M = 4096;           // B*S
    constexpr int D = 1024;

    char* ws = (char*)d_ws;
    u16*   slotA = (u16*)ws;                         // 32 MiB: qkv -> h
    char*  pB    = ws + (32u << 20);                 //  8 MiB: xb -> abuf -> nb
    char*  pC    = ws + (40u << 20);                 //  8 MiB: weight transpose
    char*  pD    = ws + (48u << 20);                 // 16 MiB: aout -> mout
    char*  pE    = ws + (64u << 20);                 // 16 MiB: n (fp32)

    u16*   xb   = (u16*)pB;
    u16*   wT   = (u16*)pC;
    u16*   qkv  = slotA;
    u16*   abuf = (u16*)pB;
    float* aout = (float*)pD;
    float* nbuf = (float*)pE;
    u16*   nb   = (u16*)pB;
    u16*   h    = slotA;
    float* mout = (float*)pD;

    dim3 blk(256);

    cvt_bf16<<<dim3(4096), blk, 0, stream>>>(x, xb, M * D / 4);

    transpose_bf16<<<dim3(3072 / 32, 1024 / 32), blk, 0, stream>>>(w_attn, wT, 1024, 3072);
    gemm_db<128, false, u16><<<dim3((M / 128) * (3072 / 128)), blk, 0, stream>>>(
        xb, wT, b_attn, qkv, M, 3072, 1024, 3072);

    attn_kernel<<<dim3(512), blk, 0, stream>>>(qkv, abuf);

    transpose_bf16<<<dim3(1024 / 32, 1024 / 32), blk, 0, stream>>>(w_aproj, wT, 1024, 1024);
    gemm_db<64, false, float><<<dim3((M / 128) * (1024 / 64)), blk, 0, stream>>>(
        abuf, wT, b_aproj, aout, M, 1024, 1024, 1024);

    resln<true><<<dim3(M), blk, 0, stream>>>(x, aout, g1, b1, nbuf, nb);

    transpose_bf16<<<dim3(4096 / 32, 1024 / 32), blk, 0, stream>>>(w_fc, wT, 1024, 4096);
    gemm_db<128, true, u16><<<dim3((M / 128) * (4096 / 128)), blk, 0, stream>>>(
        nb, wT, b_fc, h, M, 4096, 1024, 4096);

    transpose_bf16<<<dim3(1024 / 32, 4096 / 32), blk, 0, stream>>>(w_mproj, wT, 4096, 1024);
    gemm_db<64, false, float><<<dim3((M / 128) * (1024 / 64)), blk, 0, stream>>>(
        h, wT, b_mproj, mout, M, 1024, 4096, 1024);

    resln<false><<<dim3(M), blk, 0, stream>>>(nbuf, mout, g2, b2, out, nullptr);
}

// Round 8
// 314.102 us; speedup vs baseline: 3.6223x; 1.0003x over previous
//
#include <hip/hip_runtime.h>
#include <type_traits>

// ---------------------------------------------------------------------------
// GPT block forward: B=2, S=2048, D=1024, H=16, DH=64
// Round 8: attention — paired q-tiles (uniform 34-chunk blocks, grid 256),
// double-buffered K/V staging (K via global_load_lds + pre-swizzled src,
// V reg-staged with issue-early/write-late), merged 64-kv online softmax.
// GEMM/LN unchanged from round 5/7.
// ---------------------------------------------------------------------------

typedef unsigned short u16;
typedef short s16x8 __attribute__((ext_vector_type(8)));
typedef unsigned short u16x4 __attribute__((ext_vector_type(4)));
typedef float f32x4 __attribute__((ext_vector_type(4)));
typedef float f32x16 __attribute__((ext_vector_type(16)));

__device__ __forceinline__ u16 f2b(float f) {
    union { float f; unsigned u; } x{f};
    unsigned r = x.u + 0x7FFFu + ((x.u >> 16) & 1u);  // RNE
    return (u16)(r >> 16);
}

__device__ __forceinline__ f32x4 mfma16(s16x8 a, s16x8 b, f32x4 c) {
    return __builtin_amdgcn_mfma_f32_16x16x32_bf16(a, b, c, 0, 0, 0);
}

__device__ __forceinline__ f32x16 mfma32(s16x8 a, s16x8 b, f32x16 c) {
    return __builtin_amdgcn_mfma_f32_32x32x16_bf16(a, b, c, 0, 0, 0);
}

__device__ __forceinline__ int cvtpk(float a, float b) {
    int r;
    asm("v_cvt_pk_bf16_f32 %0, %1, %2" : "=v"(r) : "v"(a), "v"(b));
    return r;
}

__device__ __forceinline__ void gld_lds16(const u16* g, u16* l) {
    __builtin_amdgcn_global_load_lds(
        (const __attribute__((address_space(1))) void*)g,
        (__attribute__((address_space(3))) void*)l, 16, 0, 0);
}

// --------------------------- fp32 -> bf16 convert ---------------------------
__global__ __launch_bounds__(256) void cvt_bf16(const float* __restrict__ in,
                                                u16* __restrict__ out, int n4) {
    int i = blockIdx.x * 256 + threadIdx.x;
    if (i < n4) {
        float4 v = ((const float4*)in)[i];
        u16x4 o = {f2b(v.x), f2b(v.y), f2b(v.z), f2b(v.w)};
        ((u16x4*)out)[i] = o;
    }
}

// ------------------- transpose fp32 [K,N] -> bf16 [N,K] ---------------------
__global__ __launch_bounds__(256) void transpose_bf16(const float* __restrict__ W,
                                                      u16* __restrict__ WT,
                                                      int K, int N) {
    __shared__ float t[32][33];
    int tx = threadIdx.x & 31, ty = threadIdx.x >> 5;
    int n0 = blockIdx.x * 32, k0 = blockIdx.y * 32;
    #pragma unroll
    for (int r = ty; r < 32; r += 8)
        t[r][tx] = W[(size_t)(k0 + r) * N + n0 + tx];
    __syncthreads();
    #pragma unroll
    for (int r = ty; r < 32; r += 8)
        WT[(size_t)(n0 + r) * K + k0 + tx] = f2b(t[tx][r]);
}

// ------------------ MFMA GEMM, 2-phase double-buffered ----------------------
template<int BN, bool GELU, typename OT>
__global__ __launch_bounds__(256) void gemm_db(const u16* __restrict__ A,
                                               const u16* __restrict__ BT,
                                               const float* __restrict__ bias,
                                               OT* __restrict__ C,
                                               int M, int N, int K, int ldc) {
    constexpr int NF = BN / 32;
    constexpr int BNI = BN / 32;
    __shared__ u16 As[2][128 * 64];
    __shared__ u16 Bs[2][BN * 64];

    int t = threadIdx.x;
    int w = t >> 6, l = t & 63, l16 = l & 15, lh = l >> 4;
    int wr = w >> 1, wc = w & 1;

    int nbm = M >> 7;
    int cpx = gridDim.x >> 3;
    int id = blockIdx.x;
    int id2 = (id & 7) * cpx + (id >> 3);
    size_t m0 = (size_t)(id2 % nbm) * 128;
    size_t n0 = (size_t)(id2 / nbm) * BN;

    int rowA = t >> 3;
    int gc = t & 7;
    int gc2 = gc ^ (((rowA >> 2) & 1) << 1) ^ (((rowA >> 3) & 1) << 2);
    const u16* Ag = A + (m0 + rowA) * (size_t)K + gc2 * 8;
    const u16* Bg = BT + (n0 + rowA) * (size_t)K + gc2 * 8;
    int wbase = w * 512;

    f32x4 acc[4][NF] = {};
    int cxor = (((l16 >> 2) & 1) << 4) ^ (((l16 >> 3) & 1) << 5);

    #pragma unroll
    for (int j = 0; j < 4; ++j)
        gld_lds16(Ag + (size_t)j * 32 * K, &As[0][j * 2048 + wbase]);
    #pragma unroll
    for (int j = 0; j < BNI; ++j)
        gld_lds16(Bg + (size_t)j * 32 * K, &Bs[0][j * 2048 + wbase]);
    __syncthreads();

    int cur = 0;
    for (int k0 = 0; k0 < K; k0 += 64) {
        if (k0 + 64 < K) {
            const u16* Ap = Ag + k0 + 64;
            #pragma unroll
            for (int j = 0; j < 4; ++j)
                gld_lds16(Ap + (size_t)j * 32 * K, &As[cur ^ 1][j * 2048 + wbase]);
            const u16* Bp = Bg + k0 + 64;
            #pragma unroll
            for (int j = 0; j < BNI; ++j)
                gld_lds16(Bp + (size_t)j * 32 * K, &Bs[cur ^ 1][j * 2048 + wbase]);
        }
        __builtin_amdgcn_s_setprio(1);
        #pragma unroll
        for (int ks = 0; ks < 2; ++ks) {
            s16x8 af[4], bf[NF];
            #pragma unroll
            for (int fm = 0; fm < 4; ++fm) {
                int row = wr * 64 + fm * 16 + l16;
                int col = (ks * 32 + lh * 8) ^ cxor;
                af[fm] = *(const s16x8*)&As[cur][row * 64 + col];
            }
            #pragma unroll
            for (int fn = 0; fn < NF; ++fn) {
                int row = wc * (BN / 2) + fn * 16 + l16;
                int col = (ks * 32 + lh * 8) ^ cxor;
                bf[fn] = *(const s16x8*)&Bs[cur][row * 64 + col];
            }
            #pragma unroll
            for (int fm = 0; fm < 4; ++fm)
                #pragma unroll
                for (int fn = 0; fn < NF; ++fn)
                    acc[fm][fn] = mfma16(af[fm], bf[fn], acc[fm][fn]);
        }
        __builtin_amdgcn_s_setprio(0);
        __syncthreads();
        cur ^= 1;
    }

    #pragma unroll
    for (int fn = 0; fn < NF; ++fn) {
        size_t col = n0 + wc * (BN / 2) + fn * 16 + l16;
        float bs = bias[col];
        #pragma unroll
        for (int fm = 0; fm < 4; ++fm) {
            size_t row0 = m0 + wr * 64 + fm * 16 + lh * 4;
            #pragma unroll
            for (int i = 0; i < 4; ++i) {
                float v = acc[fm][fn][i] + bs;
                if constexpr (GELU) {
                    float x3 = v * v * v;
                    v = 0.5f * v * (1.f + tanhf(0.7978845608f * (v + 0.044715f * x3)));
                }
                if constexpr (std::is_same<OT, u16>::value)
                    C[(row0 + i) * ldc + col] = f2b(v);
                else
                    C[(row0 + i) * ldc + col] = v;
            }
        }
    }
}

// --------------------------- causal attention -------------------------------
// Block = (pair pr, bh): processes q-tile qt=pr then qt=15-pr (uniform 34
// chunks). 4 waves x 32 q-rows per tile. Per 64-kv chunk: K via 2x
// global_load_lds (pre-swizzled src, granule g^(r&7)), V reg-loaded early /
// scatter-written late (swizzle kv^((d&7)<<3)); double-buffered; one barrier.
// Swapped QK^T (mfma32(K,Q)): lane owns q=l&31; merged 64-kv online softmax;
// P->PV A-frags via cvt_pk + shfl_xor(32) exchange (verified round 7).
__global__ __launch_bounds__(256, 1) void attn_kernel(const u16* __restrict__ qkv,
                                                      u16* __restrict__ abuf) {
    constexpr int S = 2048, D3 = 3072, Dm = 1024;
    __shared__ u16 Kl[2][64 * 64];
    __shared__ u16 Vt[2][64 * 64];

    int t = threadIdx.x;
    int w = t >> 6, l = t & 63;
    int l32 = l & 31, hi = l >> 5;
    int pr = blockIdx.x >> 5;
    int bh = blockIdx.x & 31;
    int b = bh >> 4, h = bh & 15;
    size_t base = (size_t)b * S * D3;

    // K staging: thread t -> granules t and 256+t; row r=g>>3, src granule
    // gc^(r&7); LDS dest linear (wave-uniform base + lane*16).
    int rK0 = t >> 3, gK = t & 7;
    int rK1 = rK0 + 32;
    size_t koff0 = (size_t)rK0 * D3 + (size_t)((gK ^ (rK0 & 7)) * 8);
    size_t koff1 = (size_t)rK1 * D3 + (size_t)((gK ^ (rK1 & 7)) * 8);
    const u16* kbase = qkv + base + Dm + h * 64;
    const u16* vbase = qkv + base + 2 * Dm + h * 64 + w * 16;

    constexpr float cexp = 0.18033688011112042f;   // 0.125 * log2(e)
    constexpr float THR = 64.0f;                    // defer-max threshold
    int xg = l32 & 7;

    #pragma unroll 1
    for (int ph = 0; ph < 2; ++ph) {
        int qt = ph ? (15 - pr) : pr;
        int qb = qt * 128 + w * 32;
        int nst = 2 * (qt + 1);

        s16x8 qf[4];
        const u16* qp = qkv + base + (size_t)(qb + l32) * D3 + h * 64 + hi * 8;
        #pragma unroll
        for (int kk = 0; kk < 4; ++kk)
            qf[kk] = *(const s16x8*)(qp + kk * 16);

        f32x16 O0 = {}, O1 = {};
        float m = -1e30f, lr = 0.f;

        // prologue: stage chunk 0 into buf 0
        gld_lds16(kbase + koff0, &Kl[0][w * 512]);
        gld_lds16(kbase + koff1, &Kl[0][2048 + w * 512]);
        {
            const u16* vp = vbase + (size_t)l * D3;
            s16x8 pv0 = *(const s16x8*)vp;
            s16x8 pv1 = *(const s16x8*)(vp + 8);
            #pragma unroll
            for (int e = 0; e < 8; ++e) {
                int d0 = w * 16 + e, d1 = w * 16 + 8 + e;
                Vt[0][d0 * 64 + (l ^ ((d0 & 7) << 3))] = (u16)pv0[e];
                Vt[0][d1 * 64 + (l ^ ((d1 & 7) << 3))] = (u16)pv1[e];
            }
        }
        __syncthreads();

        #pragma unroll 1
        for (int sc = 0; sc < nst; ++sc) {
            int cur = sc & 1;
            bool pre = (sc + 1 < nst);
            s16x8 v0, v1;
            if (pre) {
                size_t koffc = (size_t)(sc + 1) * 64 * D3;
                gld_lds16(kbase + koffc + koff0, &Kl[cur ^ 1][w * 512]);
                gld_lds16(kbase + koffc + koff1, &Kl[cur ^ 1][2048 + w * 512]);
                const u16* vp = vbase + (size_t)((sc + 1) * 64 + l) * D3;
                v0 = *(const s16x8*)vp;
                v1 = *(const s16x8*)(vp + 8);
            }

            // -------- compute on buf[cur], kvb = sc*64 --------
            int kvb = sc * 64;
            int navail = ((qb - kvb) >> 5) + 1;
            if (navail > 0) {
                if (navail > 2) navail = 2;
                const u16* Kc = Kl[cur];
                const u16* Vc = Vt[cur];
                f32x16 sa0 = {}, sa1 = {};
                #pragma unroll
                for (int kk = 0; kk < 4; ++kk) {
                    s16x8 kf = *(const s16x8*)&Kc[l32 * 64 + (((2 * kk + hi) ^ xg) * 8)];
                    sa0 = mfma32(kf, qf[kk], sa0);
                }
                if (navail == 2) {
                    #pragma unroll
                    for (int kk = 0; kk < 4; ++kk) {
                        s16x8 kf = *(const s16x8*)&Kc[(32 + l32) * 64 + (((2 * kk + hi) ^ xg) * 8)];
                        sa1 = mfma32(kf, qf[kk], sa1);
                    }
                }
                bool diag0 = (kvb == qb);
                bool diag1 = (kvb + 32 == qb);
                float p[32];
                float mx = -1e30f;
                #pragma unroll
                for (int reg = 0; reg < 16; ++reg) {
                    int kvloc = (reg & 3) + 8 * (reg >> 2) + 4 * hi;
                    float s0 = sa0[reg];
                    if (diag0 && kvloc > l32) s0 = -1e30f;
                    p[reg] = s0;
                    mx = fmaxf(mx, s0);
                }
                if (navail == 2) {
                    #pragma unroll
                    for (int reg = 0; reg < 16; ++reg) {
                        int kvloc = (reg & 3) + 8 * (reg >> 2) + 4 * hi;
                        float s1 = sa1[reg];
                        if (diag1 && kvloc > l32) s1 = -1e30f;
                        p[16 + reg] = s1;
                        mx = fmaxf(mx, s1);
                    }
                }
                mx = fmaxf(mx, __shfl_xor(mx, 32));
                if (!__all(mx <= m + THR)) {          // defer-max (T13)
                    float mn = fmaxf(m, mx);
                    float a_ = exp2f(cexp * (m - mn));
                    m = mn;
                    #pragma unroll
                    for (int reg = 0; reg < 16; ++reg) {
                        int src = (reg & 3) + 8 * (reg >> 2) + 4 * hi;
                        float aq = __shfl(a_, src);
                        O0[reg] *= aq;
                        O1[reg] *= aq;
                    }
                    lr *= a_;
                }
                float rs = 0.f;
                #pragma unroll
                for (int reg = 0; reg < 16; ++reg) {
                    p[reg] = exp2f(cexp * (p[reg] - m));
                    rs += p[reg];
                }
                if (navail == 2) {
                    #pragma unroll
                    for (int reg = 16; reg < 32; ++reg) {
                        p[reg] = exp2f(cexp * (p[reg] - m));
                        rs += p[reg];
                    }
                }
                rs += __shfl_xor(rs, 32);
                lr += rs;

                #pragma unroll
                for (int c = 0; c < 4; ++c) {
                    if (c < navail * 2) {
                        int pb = (c >> 1) * 16 + (c & 1) * 8;
                        int pk01 = cvtpk(p[pb + 0], p[pb + 1]);
                        int pk23 = cvtpk(p[pb + 2], p[pb + 3]);
                        int pk45 = cvtpk(p[pb + 4], p[pb + 5]);
                        int pk67 = cvtpk(p[pb + 6], p[pb + 7]);
                        int sx01 = __shfl_xor(pk01, 32);
                        int sx23 = __shfl_xor(pk23, 32);
                        int sx45 = __shfl_xor(pk45, 32);
                        int sx67 = __shfl_xor(pk67, 32);
                        union { int i[4]; s16x8 v; } u;
                        u.i[0] = hi ? sx45 : pk01;
                        u.i[1] = hi ? sx67 : pk23;
                        u.i[2] = hi ? pk45 : sx01;
                        u.i[3] = hi ? pk67 : sx23;
                        int go = ((c * 2 + hi) ^ xg) * 8;
                        s16x8 vb0 = *(const s16x8*)&Vc[l32 * 64 + go];
                        O0 = mfma32(u.v, vb0, O0);
                        s16x8 vb1 = *(const s16x8*)&Vc[(32 + l32) * 64 + go];
                        O1 = mfma32(u.v, vb1, O1);
                    }
                }
            }
            // -------- end compute --------

            if (pre) {
                #pragma unroll
                for (int e = 0; e < 8; ++e) {
                    int d0 = w * 16 + e, d1 = w * 16 + 8 + e;
                    Vt[cur ^ 1][d0 * 64 + (l ^ ((d0 & 7) << 3))] = (u16)v0[e];
                    Vt[cur ^ 1][d1 * 64 + (l ^ ((d1 & 7) << 3))] = (u16)v1[e];
                }
            }
            __syncthreads();
        }

        // epilogue
        float invl = 1.f / lr;
        size_t obase = (size_t)b * S * 1024 + h * 64;
        #pragma unroll
        for (int reg = 0; reg < 16; ++reg) {
            int src = (reg & 3) + 8 * (reg >> 2) + 4 * hi;
            float iq = __shfl(invl, src);
            size_t row = obase + (size_t)(qb + src) * 1024;
            abuf[row + l32] = f2b(O0[reg] * iq);
            abuf[row + 32 + l32] = f2b(O1[reg] * iq);
        }
    }
}

// --------------------- residual + LayerNorm (row = 1024) --------------------
template<bool WB>
__global__ __launch_bounds__(256) void resln(const float* __restrict__ xa,
                                             const float* __restrict__ xb2,
                                             const float* __restrict__ g,
                                             const float* __restrict__ be,
                                             float* __restrict__ outf,
                                             u16* __restrict__ outb) {
    int row = blockIdx.x;
    int t = threadIdx.x;
    size_t base = (size_t)row * 1024 + t * 4;
    float4 va = *(const float4*)(xa + base);
    float4 vb = *(const float4*)(xb2 + base);
    float v0 = va.x + vb.x, v1 = va.y + vb.y, v2 = va.z + vb.z, v3 = va.w + vb.w;
    float s1 = v0 + v1 + v2 + v3;
    float s2 = v0 * v0 + v1 * v1 + v2 * v2 + v3 * v3;
    #pragma unroll
    for (int off = 32; off >= 1; off >>= 1) {
        s1 += __shfl_down(s1, off);
        s2 += __shfl_down(s2, off);
    }
    __shared__ float r1[4], r2[4];
    if ((t & 63) == 0) { r1[t >> 6] = s1; r2[t >> 6] = s2; }
    __syncthreads();
    s1 = r1[0] + r1[1] + r1[2] + r1[3];
    s2 = r2[0] + r2[1] + r2[2] + r2[3];
    float mean = s1 * (1.f / 1024.f);
    float var = fmaxf((s2 - 1024.f * mean * mean) * (1.f / 1023.f), 0.f);
    float inv = 1.f / (sqrtf(var) + 1e-6f);
    int col = t * 4;
    float y0 = g[col + 0] * ((v0 - mean) * inv) + be[col + 0];
    float y1 = g[col + 1] * ((v1 - mean) * inv) + be[col + 1];
    float y2 = g[col + 2] * ((v2 - mean) * inv) + be[col + 2];
    float y3 = g[col + 3] * ((v3 - mean) * inv) + be[col + 3];
    float4 o = {y0, y1, y2, y3};
    *(float4*)(outf + base) = o;
    if constexpr (WB) {
        u16x4 ob = {f2b(y0), f2b(y1), f2b(y2), f2b(y3)};
        *(u16x4*)(outb + base) = ob;
    }
}

// ---------------------------------------------------------------------------
extern "C" void kernel_launch(void* const* d_in, const int* in_sizes, int n_in,
                              void* d_out, int out_size, void* d_ws, size_t ws_size,
                              hipStream_t stream) {
    (void)in_sizes; (void)n_in; (void)out_size; (void)ws_size;
    const float* x       = (const float*)d_in[0];
    const float* w_attn  = (const float*)d_in[1];
    const float* b_attn  = (const float*)d_in[2];
    const float* w_aproj = (const float*)d_in[3];
    const float* b_aproj = (const float*)d_in[4];
    const float* g1      = (const float*)d_in[5];
    const float* b1      = (const float*)d_in[6];
    const float* w_fc    = (const float*)d_in[7];
    const float* b_fc    = (const float*)d_in[8];
    const float* w_mproj = (const float*)d_in[9];
    const float* b_mproj = (const float*)d_in[10];
    const float* g2      = (const float*)d_in[11];
    const float* b2      = (const float*)d_in[12];
    float* out = (float*)d_out;

    constexpr int M = 4096;           // B*S
    constexpr int D = 1024;

    char* ws = (char*)d_ws;
    u16*   slotA = (u16*)ws;                         // 32 MiB: qkv -> h
    char*  pB    = ws + (32u << 20);                 //  8 MiB: xb -> abuf -> nb
    char*  pC    = ws + (40u << 20);                 //  8 MiB: weight transpose
    char*  pD    = ws + (48u << 20);                 // 16 MiB: aout -> mout
    char*  pE    = ws + (64u << 20);                 // 16 MiB: n (fp32)

    u16*   xb   = (u16*)pB;
    u16*   wT   = (u16*)pC;
    u16*   qkv  = slotA;
    u16*   abuf = (u16*)pB;
    float* aout = (float*)pD;
    float* nbuf = (float*)pE;
    u16*   nb   = (u16*)pB;
    u16*   h    = slotA;
    float* mout = (float*)pD;

    dim3 blk(256);

    cvt_bf16<<<dim3(4096), blk, 0, stream>>>(x, xb, M * D / 4);

    transpose_bf16<<<dim3(3072 / 32, 1024 / 32), blk, 0, stream>>>(w_attn, wT, 1024, 3072);
    gemm_db<128, false, u16><<<dim3((M / 128) * (3072 / 128)), blk, 0, stream>>>(
        xb, wT, b_attn, qkv, M, 3072, 1024, 3072);

    attn_kernel<<<dim3(256), blk, 0, stream>>>(qkv, abuf);

    transpose_bf16<<<dim3(1024 / 32, 1024 / 32), blk, 0, stream>>>(w_aproj, wT, 1024, 1024);
    gemm_db<64, false, float><<<dim3((M / 128) * (1024 / 64)), blk, 0, stream>>>(
        abuf, wT, b_aproj, aout, M, 1024, 1024, 1024);

    resln<true><<<dim3(M), blk, 0, stream>>>(x, aout, g1, b1, nbuf, nb);

    transpose_bf16<<<dim3(4096 / 32, 1024 / 32), blk, 0, stream>>>(w_fc, wT, 1024, 4096);
    gemm_db<128, true, u16><<<dim3((M / 128) * (4096 / 128)), blk, 0, stream>>>(
        nb, wT, b_fc, h, M, 4096, 1024, 4096);

    transpose_bf16<<<dim3(1024 / 32, 4096 / 32), blk, 0, stream>>>(w_mproj, wT, 4096, 1024);
    gemm_db<64, false, float><<<dim3((M / 128) * (1024 / 64)), blk, 0, stream>>>(
        h, wT, b_mproj, mout, M, 1024, 4096, 1024);

    resln<false><<<dim3(M), blk, 0, stream>>>(nbuf, mout, g2, b2, out, nullptr);
}

// Round 9
// 302.831 us; speedup vs baseline: 3.7571x; 1.0372x over previous
//
#include <hip/hip_runtime.h>
#include <type_traits>

// ---------------------------------------------------------------------------
// GPT block forward: B=2, S=2048, D=1024, H=16, DH=64
// Round 9: attention kv-split x3 (flash-decoding): grid 768 (3 blocks/CU,
// 3 waves/SIMD), unnormalized partials + exact merge kernel.
// GEMM/LN unchanged from round 5/7/8.
// ---------------------------------------------------------------------------

typedef unsigned short u16;
typedef short s16x8 __attribute__((ext_vector_type(8)));
typedef unsigned short u16x4 __attribute__((ext_vector_type(4)));
typedef float f32x4 __attribute__((ext_vector_type(4)));
typedef float f32x16 __attribute__((ext_vector_type(16)));

__device__ __forceinline__ u16 f2b(float f) {
    union { float f; unsigned u; } x{f};
    unsigned r = x.u + 0x7FFFu + ((x.u >> 16) & 1u);  // RNE
    return (u16)(r >> 16);
}

__device__ __forceinline__ float b2f(u16 v) {
    union { unsigned u; float f; } x;
    x.u = ((unsigned)v) << 16;
    return x.f;
}

__device__ __forceinline__ f32x4 mfma16(s16x8 a, s16x8 b, f32x4 c) {
    return __builtin_amdgcn_mfma_f32_16x16x32_bf16(a, b, c, 0, 0, 0);
}

__device__ __forceinline__ f32x16 mfma32(s16x8 a, s16x8 b, f32x16 c) {
    return __builtin_amdgcn_mfma_f32_32x32x16_bf16(a, b, c, 0, 0, 0);
}

__device__ __forceinline__ int cvtpk(float a, float b) {
    int r;
    asm("v_cvt_pk_bf16_f32 %0, %1, %2" : "=v"(r) : "v"(a), "v"(b));
    return r;
}

__device__ __forceinline__ void gld_lds16(const u16* g, u16* l) {
    __builtin_amdgcn_global_load_lds(
        (const __attribute__((address_space(1))) void*)g,
        (__attribute__((address_space(3))) void*)l, 16, 0, 0);
}

// --------------------------- fp32 -> bf16 convert ---------------------------
__global__ __launch_bounds__(256) void cvt_bf16(const float* __restrict__ in,
                                                u16* __restrict__ out, int n4) {
    int i = blockIdx.x * 256 + threadIdx.x;
    if (i < n4) {
        float4 v = ((const float4*)in)[i];
        u16x4 o = {f2b(v.x), f2b(v.y), f2b(v.z), f2b(v.w)};
        ((u16x4*)out)[i] = o;
    }
}

// ------------------- transpose fp32 [K,N] -> bf16 [N,K] ---------------------
__global__ __launch_bounds__(256) void transpose_bf16(const float* __restrict__ W,
                                                      u16* __restrict__ WT,
                                                      int K, int N) {
    __shared__ float t[32][33];
    int tx = threadIdx.x & 31, ty = threadIdx.x >> 5;
    int n0 = blockIdx.x * 32, k0 = blockIdx.y * 32;
    #pragma unroll
    for (int r = ty; r < 32; r += 8)
        t[r][tx] = W[(size_t)(k0 + r) * N + n0 + tx];
    __syncthreads();
    #pragma unroll
    for (int r = ty; r < 32; r += 8)
        WT[(size_t)(n0 + r) * K + k0 + tx] = f2b(t[tx][r]);
}

// ------------------ MFMA GEMM, 2-phase double-buffered ----------------------
template<int BN, bool GELU, typename OT>
__global__ __launch_bounds__(256) void gemm_db(const u16* __restrict__ A,
                                               const u16* __restrict__ BT,
                                               const float* __restrict__ bias,
                                               OT* __restrict__ C,
                                               int M, int N, int K, int ldc) {
    constexpr int NF = BN / 32;
    constexpr int BNI = BN / 32;
    __shared__ u16 As[2][128 * 64];
    __shared__ u16 Bs[2][BN * 64];

    int t = threadIdx.x;
    int w = t >> 6, l = t & 63, l16 = l & 15, lh = l >> 4;
    int wr = w >> 1, wc = w & 1;

    int nbm = M >> 7;
    int cpx = gridDim.x >> 3;
    int id = blockIdx.x;
    int id2 = (id & 7) * cpx + (id >> 3);
    size_t m0 = (size_t)(id2 % nbm) * 128;
    size_t n0 = (size_t)(id2 / nbm) * BN;

    int rowA = t >> 3;
    int gc = t & 7;
    int gc2 = gc ^ (((rowA >> 2) & 1) << 1) ^ (((rowA >> 3) & 1) << 2);
    const u16* Ag = A + (m0 + rowA) * (size_t)K + gc2 * 8;
    const u16* Bg = BT + (n0 + rowA) * (size_t)K + gc2 * 8;
    int wbase = w * 512;

    f32x4 acc[4][NF] = {};
    int cxor = (((l16 >> 2) & 1) << 4) ^ (((l16 >> 3) & 1) << 5);

    #pragma unroll
    for (int j = 0; j < 4; ++j)
        gld_lds16(Ag + (size_t)j * 32 * K, &As[0][j * 2048 + wbase]);
    #pragma unroll
    for (int j = 0; j < BNI; ++j)
        gld_lds16(Bg + (size_t)j * 32 * K, &Bs[0][j * 2048 + wbase]);
    __syncthreads();

    int cur = 0;
    for (int k0 = 0; k0 < K; k0 += 64) {
        if (k0 + 64 < K) {
            const u16* Ap = Ag + k0 + 64;
            #pragma unroll
            for (int j = 0; j < 4; ++j)
                gld_lds16(Ap + (size_t)j * 32 * K, &As[cur ^ 1][j * 2048 + wbase]);
            const u16* Bp = Bg + k0 + 64;
            #pragma unroll
            for (int j = 0; j < BNI; ++j)
                gld_lds16(Bp + (size_t)j * 32 * K, &Bs[cur ^ 1][j * 2048 + wbase]);
        }
        __builtin_amdgcn_s_setprio(1);
        #pragma unroll
        for (int ks = 0; ks < 2; ++ks) {
            s16x8 af[4], bf[NF];
            #pragma unroll
            for (int fm = 0; fm < 4; ++fm) {
                int row = wr * 64 + fm * 16 + l16;
                int col = (ks * 32 + lh * 8) ^ cxor;
                af[fm] = *(const s16x8*)&As[cur][row * 64 + col];
            }
            #pragma unroll
            for (int fn = 0; fn < NF; ++fn) {
                int row = wc * (BN / 2) + fn * 16 + l16;
                int col = (ks * 32 + lh * 8) ^ cxor;
                bf[fn] = *(const s16x8*)&Bs[cur][row * 64 + col];
            }
            #pragma unroll
            for (int fm = 0; fm < 4; ++fm)
                #pragma unroll
                for (int fn = 0; fn < NF; ++fn)
                    acc[fm][fn] = mfma16(af[fm], bf[fn], acc[fm][fn]);
        }
        __builtin_amdgcn_s_setprio(0);
        __syncthreads();
        cur ^= 1;
    }

    #pragma unroll
    for (int fn = 0; fn < NF; ++fn) {
        size_t col = n0 + wc * (BN / 2) + fn * 16 + l16;
        float bs = bias[col];
        #pragma unroll
        for (int fm = 0; fm < 4; ++fm) {
            size_t row0 = m0 + wr * 64 + fm * 16 + lh * 4;
            #pragma unroll
            for (int i = 0; i < 4; ++i) {
                float v = acc[fm][fn][i] + bs;
                if constexpr (GELU) {
                    float x3 = v * v * v;
                    v = 0.5f * v * (1.f + tanhf(0.7978845608f * (v + 0.044715f * x3)));
                }
                if constexpr (std::is_same<OT, u16>::value)
                    C[(row0 + i) * ldc + col] = f2b(v);
                else
                    C[(row0 + i) * ldc + col] = v;
            }
        }
    }
}

// --------------------------- causal attention -------------------------------
// kv-split x3: block = (third, pair pr, bh). Processes q-tile qt=pr then
// qt=15-pr, kv-chunk range [nst*third/3, nst*(third+1)/3) of nst=2(qt+1).
// Writes UNNORMALIZED O (bf16) to part[third] and (m,lr) stats; merge_attn
// combines exactly. Per-chunk pipeline identical to round 8 (verified).
__global__ __launch_bounds__(256) void attn_kernel(const u16* __restrict__ qkv,
                                                   u16* __restrict__ p0,
                                                   u16* __restrict__ p1,
                                                   u16* __restrict__ p2,
                                                   float2* __restrict__ stats) {
    constexpr int S = 2048, D3 = 3072, Dm = 1024;
    __shared__ u16 Kl[2][64 * 64];
    __shared__ u16 Vt[2][64 * 64];

    int t = threadIdx.x;
    int w = t >> 6, l = t & 63;
    int l32 = l & 31, hi = l >> 5;
    int bid = blockIdx.x;
    int bh = bid & 31;
    int pr = (bid >> 5) & 7;
    int third = bid >> 8;               // 0..2
    int b = bh >> 4, h = bh & 15;
    size_t base = (size_t)b * S * D3;

    u16* pout = third == 0 ? p0 : (third == 1 ? p1 : p2);

    int rK0 = t >> 3, gK = t & 7;
    int rK1 = rK0 + 32;
    size_t koff0 = (size_t)rK0 * D3 + (size_t)((gK ^ (rK0 & 7)) * 8);
    size_t koff1 = (size_t)rK1 * D3 + (size_t)((gK ^ (rK1 & 7)) * 8);
    const u16* kbase = qkv + base + Dm + h * 64;
    const u16* vbase = qkv + base + 2 * Dm + h * 64 + w * 16;

    constexpr float cexp = 0.18033688011112042f;   // 0.125 * log2(e)
    constexpr float THR = 64.0f;                    // defer-max threshold
    int xg = l32 & 7;

    #pragma unroll 1
    for (int ph = 0; ph < 2; ++ph) {
        int qt = ph ? (15 - pr) : pr;
        int qb = qt * 128 + w * 32;
        int nst = 2 * (qt + 1);
        int c0 = (nst * third) / 3;
        int c1 = (nst * (third + 1)) / 3;

        f32x16 O0 = {}, O1 = {};
        float m = -1e30f, lr = 0.f;

        if (c0 < c1) {
            s16x8 qf[4];
            const u16* qp = qkv + base + (size_t)(qb + l32) * D3 + h * 64 + hi * 8;
            #pragma unroll
            for (int kk = 0; kk < 4; ++kk)
                qf[kk] = *(const s16x8*)(qp + kk * 16);

            // prologue: stage chunk c0 into buf 0
            size_t kc0 = (size_t)c0 * 64 * D3;
            gld_lds16(kbase + kc0 + koff0, &Kl[0][w * 512]);
            gld_lds16(kbase + kc0 + koff1, &Kl[0][2048 + w * 512]);
            {
                const u16* vp = vbase + (size_t)(c0 * 64 + l) * D3;
                s16x8 pv0 = *(const s16x8*)vp;
                s16x8 pv1 = *(const s16x8*)(vp + 8);
                #pragma unroll
                for (int e = 0; e < 8; ++e) {
                    int d0 = w * 16 + e, d1 = w * 16 + 8 + e;
                    Vt[0][d0 * 64 + (l ^ ((d0 & 7) << 3))] = (u16)pv0[e];
                    Vt[0][d1 * 64 + (l ^ ((d1 & 7) << 3))] = (u16)pv1[e];
                }
            }
            __syncthreads();

            #pragma unroll 1
            for (int sc = c0; sc < c1; ++sc) {
                int cur = (sc - c0) & 1;
                bool pre = (sc + 1 < c1);
                s16x8 v0, v1;
                if (pre) {
                    size_t koffc = (size_t)(sc + 1) * 64 * D3;
                    gld_lds16(kbase + koffc + koff0, &Kl[cur ^ 1][w * 512]);
                    gld_lds16(kbase + koffc + koff1, &Kl[cur ^ 1][2048 + w * 512]);
                    const u16* vp = vbase + (size_t)((sc + 1) * 64 + l) * D3;
                    v0 = *(const s16x8*)vp;
                    v1 = *(const s16x8*)(vp + 8);
                }

                int kvb = sc * 64;
                int navail = ((qb - kvb) >> 5) + 1;
                if (navail > 0) {
                    if (navail > 2) navail = 2;
                    const u16* Kc = Kl[cur];
                    const u16* Vc = Vt[cur];
                    f32x16 sa0 = {}, sa1 = {};
                    #pragma unroll
                    for (int kk = 0; kk < 4; ++kk) {
                        s16x8 kf = *(const s16x8*)&Kc[l32 * 64 + (((2 * kk + hi) ^ xg) * 8)];
                        sa0 = mfma32(kf, qf[kk], sa0);
                    }
                    if (navail == 2) {
                        #pragma unroll
                        for (int kk = 0; kk < 4; ++kk) {
                            s16x8 kf = *(const s16x8*)&Kc[(32 + l32) * 64 + (((2 * kk + hi) ^ xg) * 8)];
                            sa1 = mfma32(kf, qf[kk], sa1);
                        }
                    }
                    bool diag0 = (kvb == qb);
                    bool diag1 = (kvb + 32 == qb);
                    float p[32];
                    float mx = -1e30f;
                    #pragma unroll
                    for (int reg = 0; reg < 16; ++reg) {
                        int kvloc = (reg & 3) + 8 * (reg >> 2) + 4 * hi;
                        float s0 = sa0[reg];
                        if (diag0 && kvloc > l32) s0 = -1e30f;
                        p[reg] = s0;
                        mx = fmaxf(mx, s0);
                    }
                    if (navail == 2) {
                        #pragma unroll
                        for (int reg = 0; reg < 16; ++reg) {
                            int kvloc = (reg & 3) + 8 * (reg >> 2) + 4 * hi;
                            float s1 = sa1[reg];
                            if (diag1 && kvloc > l32) s1 = -1e30f;
                            p[16 + reg] = s1;
                            mx = fmaxf(mx, s1);
                        }
                    }
                    mx = fmaxf(mx, __shfl_xor(mx, 32));
                    if (!__all(mx <= m + THR)) {          // defer-max (T13)
                        float mn = fmaxf(m, mx);
                        float a_ = exp2f(cexp * (m - mn));
                        m = mn;
                        #pragma unroll
                        for (int reg = 0; reg < 16; ++reg) {
                            int src = (reg & 3) + 8 * (reg >> 2) + 4 * hi;
                            float aq = __shfl(a_, src);
                            O0[reg] *= aq;
                            O1[reg] *= aq;
                        }
                        lr *= a_;
                    }
                    float rs = 0.f;
                    #pragma unroll
                    for (int reg = 0; reg < 16; ++reg) {
                        p[reg] = exp2f(cexp * (p[reg] - m));
                        rs += p[reg];
                    }
                    if (navail == 2) {
                        #pragma unroll
                        for (int reg = 16; reg < 32; ++reg) {
                            p[reg] = exp2f(cexp * (p[reg] - m));
                            rs += p[reg];
                        }
                    }
                    rs += __shfl_xor(rs, 32);
                    lr += rs;

                    #pragma unroll
                    for (int c = 0; c < 4; ++c) {
                        if (c < navail * 2) {
                            int pb = (c >> 1) * 16 + (c & 1) * 8;
                            int pk01 = cvtpk(p[pb + 0], p[pb + 1]);
                            int pk23 = cvtpk(p[pb + 2], p[pb + 3]);
                            int pk45 = cvtpk(p[pb + 4], p[pb + 5]);
                            int pk67 = cvtpk(p[pb + 6], p[pb + 7]);
                            int sx01 = __shfl_xor(pk01, 32);
                            int sx23 = __shfl_xor(pk23, 32);
                            int sx45 = __shfl_xor(pk45, 32);
                            int sx67 = __shfl_xor(pk67, 32);
                            union { int i[4]; s16x8 v; } u;
                            u.i[0] = hi ? sx45 : pk01;
                            u.i[1] = hi ? sx67 : pk23;
                            u.i[2] = hi ? pk45 : sx01;
                            u.i[3] = hi ? pk67 : sx23;
                            int go = ((c * 2 + hi) ^ xg) * 8;
                            s16x8 vb0 = *(const s16x8*)&Vc[l32 * 64 + go];
                            O0 = mfma32(u.v, vb0, O0);
                            s16x8 vb1 = *(const s16x8*)&Vc[(32 + l32) * 64 + go];
                            O1 = mfma32(u.v, vb1, O1);
                        }
                    }
                }

                if (pre) {
                    #pragma unroll
                    for (int e = 0; e < 8; ++e) {
                        int d0 = w * 16 + e, d1 = w * 16 + 8 + e;
                        Vt[cur ^ 1][d0 * 64 + (l ^ ((d0 & 7) << 3))] = (u16)v0[e];
                        Vt[cur ^ 1][d1 * 64 + (l ^ ((d1 & 7) << 3))] = (u16)v1[e];
                    }
                }
                __syncthreads();
            }
        }

        // epilogue: unnormalized partial + stats
        size_t obase = (size_t)b * S * 1024 + h * 64;
        #pragma unroll
        for (int reg = 0; reg < 16; ++reg) {
            int src = (reg & 3) + 8 * (reg >> 2) + 4 * hi;
            size_t row = obase + (size_t)(qb + src) * 1024;
            pout[row + l32] = f2b(O0[reg]);
            pout[row + 32 + l32] = f2b(O1[reg]);
        }
        if (hi == 0) {
            float2 st; st.x = m; st.y = lr;
            stats[third * 65536 + ((b * 2048 + qb + l32) * 16 + h)] = st;
        }
    }
}

// ------------------------- attention partial merge --------------------------
// out (in-place = p0): for each (rowhead, d): O = sum a_i O_i / sum a_i l_i,
// a_i = exp2(cexp*(m_i - M)), M = max m_i. Exact for any per-partial m.
__global__ __launch_bounds__(256) void merge_attn(u16* __restrict__ p0,
                                                  const u16* __restrict__ p1,
                                                  const u16* __restrict__ p2,
                                                  const float2* __restrict__ stats) {
    constexpr float cexp = 0.18033688011112042f;
    int gid = blockIdx.x * 256 + threadIdx.x;    // [0, 65536*4)
    int rh = gid >> 2;
    int dc = (gid & 3) * 16;
    int R = rh >> 4, h = rh & 15;
    size_t addr = (size_t)R * 1024 + h * 64 + dc;

    float2 s0 = stats[rh];
    float2 s1 = stats[65536 + rh];
    float2 s2 = stats[131072 + rh];
    float M = fmaxf(s0.x, fmaxf(s1.x, s2.x));
    float a0 = exp2f(cexp * (s0.x - M));
    float a1 = exp2f(cexp * (s1.x - M));
    float a2 = exp2f(cexp * (s2.x - M));
    float inv = 1.f / (a0 * s0.y + a1 * s1.y + a2 * s2.y);
    a0 *= inv; a1 *= inv; a2 *= inv;

    u16x4 o[4];
    #pragma unroll
    for (int j = 0; j < 4; ++j) {
        u16x4 q0 = *(const u16x4*)(p0 + addr + j * 4);
        u16x4 q1 = *(const u16x4*)(p1 + addr + j * 4);
        u16x4 q2 = *(const u16x4*)(p2 + addr + j * 4);
        #pragma unroll
        for (int e = 0; e < 4; ++e)
            o[j][e] = f2b(a0 * b2f(q0[e]) + a1 * b2f(q1[e]) + a2 * b2f(q2[e]));
    }
    #pragma unroll
    for (int j = 0; j < 4; ++j)
        *(u16x4*)(p0 + addr + j * 4) = o[j];
}

// --------------------- residual + LayerNorm (row = 1024) --------------------
template<bool WB>
__global__ __launch_bounds__(256) void resln(const float* __restrict__ xa,
                                             const float* __restrict__ xb2,
                                             const float* __restrict__ g,
                                             const float* __restrict__ be,
                                             float* __restrict__ outf,
                                             u16* __restrict__ outb) {
    int row = blockIdx.x;
    int t = threadIdx.x;
    size_t base = (size_t)row * 1024 + t * 4;
    float4 va = *(const float4*)(xa + base);
    float4 vb = *(const float4*)(xb2 + base);
    float v0 = va.x + vb.x, v1 = va.y + vb.y, v2 = va.z + vb.z, v3 = va.w + vb.w;
    float s1 = v0 + v1 + v2 + v3;
    float s2 = v0 * v0 + v1 * v1 + v2 * v2 + v3 * v3;
    #pragma unroll
    for (int off = 32; off >= 1; off >>= 1) {
        s1 += __shfl_down(s1, off);
        s2 += __shfl_down(s2, off);
    }
    __shared__ float r1[4], r2[4];
    if ((t & 63) == 0) { r1[t >> 6] = s1; r2[t >> 6] = s2; }
    __syncthreads();
    s1 = r1[0] + r1[1] + r1[2] + r1[3];
    s2 = r2[0] + r2[1] + r2[2] + r2[3];
    float mean = s1 * (1.f / 1024.f);
    float var = fmaxf((s2 - 1024.f * mean * mean) * (1.f / 1023.f), 0.f);
    float inv = 1.f / (sqrtf(var) + 1e-6f);
    int col = t * 4;
    float y0 = g[col + 0] * ((v0 - mean) * inv) + be[col + 0];
    float y1 = g[col + 1] * ((v1 - mean) * inv) + be[col + 1];
    float y2 = g[col + 2] * ((v2 - mean) * inv) + be[col + 2];
    float y3 = g[col + 3] * ((v3 - mean) * inv) + be[col + 3];
    float4 o = {y0, y1, y2, y3};
    *(float4*)(outf + base) = o;
    if constexpr (WB) {
        u16x4 ob = {f2b(y0), f2b(y1), f2b(y2), f2b(y3)};
        *(u16x4*)(outb + base) = ob;
    }
}

// ---------------------------------------------------------------------------
extern "C" void kernel_launch(void* const* d_in, const int* in_sizes, int n_in,
                              void* d_out, int out_size, void* d_ws, size_t ws_size,
                              hipStream_t stream) {
    (void)in_sizes; (void)n_in; (void)out_size; (void)ws_size;
    const float* x       = (const float*)d_in[0];
    const float* w_attn  = (const float*)d_in[1];
    const float* b_attn  = (const float*)d_in[2];
    const float* w_aproj = (const float*)d_in[3];
    const float* b_aproj = (const float*)d_in[4];
    const float* g1      = (const float*)d_in[5];
    const float* b1      = (const float*)d_in[6];
    const float* w_fc    = (const float*)d_in[7];
    const float* b_fc    = (const float*)d_in[8];
    const float* w_mproj = (const float*)d_in[9];
    const float* b_mproj = (const float*)d_in[10];
    const float* g2      = (const float*)d_in[11];
    const float* b2      = (const float*)d_in[12];
    float* out = (float*)d_out;

    constexpr int M = 4096;           // B*S
    constexpr int D = 1024;

    char* ws = (char*)d_ws;
    u16*   slotA = (u16*)ws;                         // 32 MiB: qkv -> h
    char*  pB    = ws + (32u << 20);                 //  8 MiB: xb -> attn part0/abuf -> nb
    char*  pC    = ws + (40u << 20);                 //  8 MiB: attn part1 -> wT
    char*  pD    = ws + (48u << 20);                 // 16 MiB: attn part2 -> aout -> mout
    char*  pE    = ws + (64u << 20);                 // 16 MiB: attn stats -> nbuf (fp32)

    u16*   xb    = (u16*)pB;
    u16*   wT    = (u16*)pC;
    u16*   qkv   = slotA;
    u16*   part0 = (u16*)pB;                         // becomes merged abuf
    u16*   part1 = (u16*)pC;
    u16*   part2 = (u16*)pD;
    float2* stat = (float2*)pE;
    u16*   abuf  = (u16*)pB;
    float* aout  = (float*)pD;
    float* nbuf  = (float*)pE;
    u16*   nb    = (u16*)pB;
    u16*   h     = slotA;
    float* mout  = (float*)pD;

    dim3 blk(256);

    cvt_bf16<<<dim3(4096), blk, 0, stream>>>(x, xb, M * D / 4);

    transpose_bf16<<<dim3(3072 / 32, 1024 / 32), blk, 0, stream>>>(w_attn, wT, 1024, 3072);
    gemm_db<128, false, u16><<<dim3((M / 128) * (3072 / 128)), blk, 0, stream>>>(
        xb, wT, b_attn, qkv, M, 3072, 1024, 3072);

    attn_kernel<<<dim3(768), blk, 0, stream>>>(qkv, part0, part1, part2, stat);
    merge_attn<<<dim3(1024), blk, 0, stream>>>(part0, part1, part2, stat);

    transpose_bf16<<<dim3(1024 / 32, 1024 / 32), blk, 0, stream>>>(w_aproj, wT, 1024, 1024);
    gemm_db<64, false, float><<<dim3((M / 128) * (1024 / 64)), blk, 0, stream>>>(
        abuf, wT, b_aproj, aout, M, 1024, 1024, 1024);

    resln<true><<<dim3(M), blk, 0, stream>>>(x, aout, g1, b1, nbuf, nb);

    transpose_bf16<<<dim3(4096 / 32, 1024 / 32), blk, 0, stream>>>(w_fc, wT, 1024, 4096);
    gemm_db<128, true, u16><<<dim3((M / 128) * (4096 / 128)), blk, 0, stream>>>(
        nb, wT, b_fc, h, M, 4096, 1024, 4096);

    transpose_bf16<<<dim3(1024 / 32, 4096 / 32), blk, 0, stream>>>(w_mproj, wT, 4096, 1024);
    gemm_db<64, false, float><<<dim3((M / 128) * (1024 / 64)), blk, 0, stream>>>(
        h, wT, b_mproj, mout, M, 1024, 4096, 1024);

    resln<false><<<dim3(M), blk, 0, stream>>>(nbuf, mout, g2, b2, out, nullptr);
}